// Round 1
// baseline (2251.653 us; speedup 1.0000x reference)
//
#include <hip/hip_runtime.h>
#include <hip/hip_bf16.h>
#include <math.h>

#define BSZ 2
#define LSEQ 2048
#define DMODEL 1024
#define DSTATE 16
#define DCONV 4
#define DINNER 2048
#define DTRANK 64
#define NPROJ (DTRANK + 2 * DSTATE) // 96

__device__ __forceinline__ float silu_f(float v) {
    return v / (1.f + expf(-v));
}
__device__ __forceinline__ float softplus_f(float v) {
    return fmaxf(v, 0.f) + log1pf(expf(-fabsf(v)));
}

// Generic tiled fp32 GEMM: C[M,N] = A[M,K(lda)] @ B[K,N]
// EPI 0: plain store (ldc = N)
// EPI 1: split: n < DINNER -> C (xb_pre), else -> C2 = silu (z path), both ldc = DINNER
// EPI 2: v = softplus(v + bias[n]), ldc = N
template <int EPI>
__global__ __launch_bounds__(256) void gemm_kernel(
    const float* __restrict__ A, const float* __restrict__ B,
    float* __restrict__ C, float* __restrict__ C2,
    const float* __restrict__ bias, int M, int N, int K, int lda) {
    __shared__ float As[16][68]; // [k][m], padded, 16B-aligned rows
    __shared__ float Bs[16][64]; // [k][n]

    const int tid = threadIdx.x;
    const int m0 = blockIdx.y * 64;
    const int n0 = blockIdx.x * 64;
    const int tx = tid & 15;  // n micro
    const int ty = tid >> 4;  // m micro
    const int arow = tid >> 2;       // 0..63
    const int ac4 = (tid & 3) * 4;   // 0,4,8,12
    const int bk = tid >> 4;         // 0..15
    const int bn4 = (tid & 15) * 4;  // 0..60

    float acc[4][4] = {};

    for (int k0 = 0; k0 < K; k0 += 16) {
        float4 av = *reinterpret_cast<const float4*>(
            &A[(size_t)(m0 + arow) * lda + k0 + ac4]);
        float4 bv;
        if (n0 + bn4 < N)
            bv = *reinterpret_cast<const float4*>(
                &B[(size_t)(k0 + bk) * N + n0 + bn4]);
        else
            bv = make_float4(0.f, 0.f, 0.f, 0.f);

        __syncthreads(); // previous tile fully consumed
        As[ac4 + 0][arow] = av.x;
        As[ac4 + 1][arow] = av.y;
        As[ac4 + 2][arow] = av.z;
        As[ac4 + 3][arow] = av.w;
        *reinterpret_cast<float4*>(&Bs[bk][bn4]) = bv;
        __syncthreads();

#pragma unroll
        for (int kk = 0; kk < 16; kk++) {
            float4 a = *reinterpret_cast<const float4*>(&As[kk][ty * 4]);
            float4 b = *reinterpret_cast<const float4*>(&Bs[kk][tx * 4]);
            acc[0][0] = fmaf(a.x, b.x, acc[0][0]);
            acc[0][1] = fmaf(a.x, b.y, acc[0][1]);
            acc[0][2] = fmaf(a.x, b.z, acc[0][2]);
            acc[0][3] = fmaf(a.x, b.w, acc[0][3]);
            acc[1][0] = fmaf(a.y, b.x, acc[1][0]);
            acc[1][1] = fmaf(a.y, b.y, acc[1][1]);
            acc[1][2] = fmaf(a.y, b.z, acc[1][2]);
            acc[1][3] = fmaf(a.y, b.w, acc[1][3]);
            acc[2][0] = fmaf(a.z, b.x, acc[2][0]);
            acc[2][1] = fmaf(a.z, b.y, acc[2][1]);
            acc[2][2] = fmaf(a.z, b.z, acc[2][2]);
            acc[2][3] = fmaf(a.z, b.w, acc[2][3]);
            acc[3][0] = fmaf(a.w, b.x, acc[3][0]);
            acc[3][1] = fmaf(a.w, b.y, acc[3][1]);
            acc[3][2] = fmaf(a.w, b.z, acc[3][2]);
            acc[3][3] = fmaf(a.w, b.w, acc[3][3]);
        }
    }

#pragma unroll
    for (int i = 0; i < 4; i++) {
#pragma unroll
        for (int j = 0; j < 4; j++) {
            int m = m0 + ty * 4 + i;
            int n = n0 + tx * 4 + j;
            if (n >= N) continue;
            float v = acc[i][j];
            if (EPI == 0) {
                C[(size_t)m * N + n] = v;
            } else if (EPI == 1) {
                if (n < DINNER)
                    C[(size_t)m * DINNER + n] = v;
                else
                    C2[(size_t)m * DINNER + (n - DINNER)] = silu_f(v);
            } else { // EPI == 2
                v = softplus_f(v + bias[n]);
                C[(size_t)m * N + n] = v;
            }
        }
    }
}

// causal depthwise conv (k=4) + bias + silu
__global__ __launch_bounds__(256) void conv_silu_kernel(
    const float* __restrict__ xin, const float* __restrict__ w,
    const float* __restrict__ bconv, float* __restrict__ xout) {
    int idx = blockIdx.x * 256 + threadIdx.x;
    if (idx >= BSZ * LSEQ * DINNER) return;
    int d = idx & (DINNER - 1);
    int bt = idx >> 11;          // / DINNER
    int t = bt & (LSEQ - 1);
    float acc = bconv[d];
    const float* wr = &w[d * 4];
#pragma unroll
    for (int k = 0; k < 4; k++) {
        int tt = t + k - 3;
        if (tt >= 0) acc = fmaf(xin[idx + (k - 3) * DINNER], wr[k], acc);
    }
    xout[idx] = silu_f(acc);
}

// selective scan: one thread per (b, d, s) chain; 16-lane reduce over s
__global__ __launch_bounds__(256) void scan_kernel(
    const float* __restrict__ xb, const float* __restrict__ dt,
    const float* __restrict__ proj, const float* __restrict__ sz,
    const float* __restrict__ A_log, const float* __restrict__ Dp,
    float* __restrict__ y) {
    const int tid = threadIdx.x;
    const int s = tid & 15;
    const int d = blockIdx.x * 16 + (tid >> 4);
    const int b = blockIdx.y;

    const float Av = -expf(A_log[d * DSTATE + s]);
    const float Dd = Dp[d];
    float h = 0.f;

    const size_t basex = (size_t)b * LSEQ * DINNER + d;
    const size_t basep = (size_t)b * LSEQ * NPROJ;

    for (int t = 0; t < LSEQ; t++) {
        float dtv = dt[basex + (size_t)t * DINNER];
        float xv = xb[basex + (size_t)t * DINNER];
        float Bv = proj[basep + t * NPROJ + DTRANK + s];
        float Cv = proj[basep + t * NPROJ + DTRANK + DSTATE + s];
        float dA = expf(dtv * Av);
        h = fmaf(dA, h, dtv * Bv * xv);
        float p = h * Cv;
        p += __shfl_xor(p, 8, 16);
        p += __shfl_xor(p, 4, 16);
        p += __shfl_xor(p, 2, 16);
        p += __shfl_xor(p, 1, 16);
        if (s == 0) {
            float szv = sz[basex + (size_t)t * DINNER];
            y[basex + (size_t)t * DINNER] = (p + Dd * xv) * szv;
        }
    }
}

extern "C" void kernel_launch(void* const* d_in, const int* in_sizes, int n_in,
                              void* d_out, int out_size, void* d_ws,
                              size_t ws_size, hipStream_t stream) {
    const float* x = (const float*)d_in[0];
    const float* W_in = (const float*)d_in[1];
    const float* conv_w = (const float*)d_in[2];
    const float* conv_b = (const float*)d_in[3];
    const float* W_xproj = (const float*)d_in[4];
    const float* W_dt = (const float*)d_in[5];
    const float* b_dt = (const float*)d_in[6];
    const float* A_log = (const float*)d_in[7];
    const float* Dp = (const float*)d_in[8];
    const float* W_out = (const float*)d_in[9];
    float* out = (float*)d_out;

    char* ws = (char*)d_ws;
    const size_t SZ = (size_t)BSZ * LSEQ * DINNER * sizeof(float); // 32 MB
    float* xb_pre = (float*)(ws);            // reused as y_full later
    float* szbuf = (float*)(ws + SZ);        // silu(z)
    float* xbbuf = (float*)(ws + 2 * SZ);    // post-conv xb
    float* dtbuf = (float*)(ws + 3 * SZ);    // dt
    float* projbuf = (float*)(ws + 4 * SZ);  // proj (4096 x 96)
    float* yfull = xb_pre;

    const int M = BSZ * LSEQ; // 4096
    dim3 blk(256);

    // 1. xz = x @ W_in  (split: xb_pre | silu(z))
    gemm_kernel<1><<<dim3((2 * DINNER) / 64, M / 64), blk, 0, stream>>>(
        x, W_in, xb_pre, szbuf, nullptr, M, 2 * DINNER, DMODEL, DMODEL);

    // 2. conv + silu
    conv_silu_kernel<<<dim3((M * DINNER) / 256), blk, 0, stream>>>(
        xb_pre, conv_w, conv_b, xbbuf);

    // 3. proj = xb @ W_xproj  (N = 96)
    gemm_kernel<0><<<dim3(2, M / 64), blk, 0, stream>>>(
        xbbuf, W_xproj, projbuf, nullptr, nullptr, M, NPROJ, DINNER, DINNER);

    // 4. dt = softplus(proj[:, :64] @ W_dt + b_dt)
    gemm_kernel<2><<<dim3(DINNER / 64, M / 64), blk, 0, stream>>>(
        projbuf, W_dt, dtbuf, nullptr, b_dt, M, DINNER, DTRANK, NPROJ);

    // 5. selective scan (+ D*xb, * silu(z))
    scan_kernel<<<dim3(DINNER / 16, BSZ), blk, 0, stream>>>(
        xbbuf, dtbuf, projbuf, szbuf, A_log, Dp, yfull);

    // 6. out = y_full @ W_out
    gemm_kernel<0><<<dim3(DMODEL / 64, M / 64), blk, 0, stream>>>(
        yfull, W_out, out, nullptr, nullptr, M, DMODEL, DINNER, DINNER);
}

// Round 2
// 1013.678 us; speedup vs baseline: 2.2213x; 2.2213x over previous
//
#include <hip/hip_runtime.h>
#include <hip/hip_bf16.h>
#include <math.h>

#define BSZ 2
#define LSEQ 2048
#define DMODEL 1024
#define DSTATE 16
#define DCONV 4
#define DINNER 2048
#define DTRANK 64
#define NPROJ (DTRANK + 2 * DSTATE) // 96
#define NC 32   // scan chunks
#define LC 64   // steps per chunk (NC*LC == LSEQ)

__device__ __forceinline__ float silu_f(float v) {
    return v / (1.f + expf(-v));
}
__device__ __forceinline__ float softplus_f(float v) {
    return fmaxf(v, 0.f) + log1pf(expf(-fabsf(v)));
}

// Generic tiled fp32 GEMM: C[M,N] = A[M,K(lda)] @ B[K,N]
// EPI 0: plain store (ldc = N)
// EPI 1: split: n < DINNER -> C (xb_pre), else -> C2 = silu (z path), both ldc = DINNER
// EPI 2: v = softplus(v + bias[n]), ldc = N
template <int EPI>
__global__ __launch_bounds__(256) void gemm_kernel(
    const float* __restrict__ A, const float* __restrict__ B,
    float* __restrict__ C, float* __restrict__ C2,
    const float* __restrict__ bias, int M, int N, int K, int lda) {
    __shared__ float As[16][68];
    __shared__ float Bs[16][64];

    const int tid = threadIdx.x;
    const int m0 = blockIdx.y * 64;
    const int n0 = blockIdx.x * 64;
    const int tx = tid & 15;
    const int ty = tid >> 4;
    const int arow = tid >> 2;
    const int ac4 = (tid & 3) * 4;
    const int bk = tid >> 4;
    const int bn4 = (tid & 15) * 4;

    float acc[4][4] = {};

    for (int k0 = 0; k0 < K; k0 += 16) {
        float4 av = *reinterpret_cast<const float4*>(
            &A[(size_t)(m0 + arow) * lda + k0 + ac4]);
        float4 bv;
        if (n0 + bn4 < N)
            bv = *reinterpret_cast<const float4*>(
                &B[(size_t)(k0 + bk) * N + n0 + bn4]);
        else
            bv = make_float4(0.f, 0.f, 0.f, 0.f);

        __syncthreads();
        As[ac4 + 0][arow] = av.x;
        As[ac4 + 1][arow] = av.y;
        As[ac4 + 2][arow] = av.z;
        As[ac4 + 3][arow] = av.w;
        *reinterpret_cast<float4*>(&Bs[bk][bn4]) = bv;
        __syncthreads();

#pragma unroll
        for (int kk = 0; kk < 16; kk++) {
            float4 a = *reinterpret_cast<const float4*>(&As[kk][ty * 4]);
            float4 b = *reinterpret_cast<const float4*>(&Bs[kk][tx * 4]);
            acc[0][0] = fmaf(a.x, b.x, acc[0][0]);
            acc[0][1] = fmaf(a.x, b.y, acc[0][1]);
            acc[0][2] = fmaf(a.x, b.z, acc[0][2]);
            acc[0][3] = fmaf(a.x, b.w, acc[0][3]);
            acc[1][0] = fmaf(a.y, b.x, acc[1][0]);
            acc[1][1] = fmaf(a.y, b.y, acc[1][1]);
            acc[1][2] = fmaf(a.y, b.z, acc[1][2]);
            acc[1][3] = fmaf(a.y, b.w, acc[1][3]);
            acc[2][0] = fmaf(a.z, b.x, acc[2][0]);
            acc[2][1] = fmaf(a.z, b.y, acc[2][1]);
            acc[2][2] = fmaf(a.z, b.z, acc[2][2]);
            acc[2][3] = fmaf(a.z, b.w, acc[2][3]);
            acc[3][0] = fmaf(a.w, b.x, acc[3][0]);
            acc[3][1] = fmaf(a.w, b.y, acc[3][1]);
            acc[3][2] = fmaf(a.w, b.z, acc[3][2]);
            acc[3][3] = fmaf(a.w, b.w, acc[3][3]);
        }
    }

#pragma unroll
    for (int i = 0; i < 4; i++) {
#pragma unroll
        for (int j = 0; j < 4; j++) {
            int m = m0 + ty * 4 + i;
            int n = n0 + tx * 4 + j;
            if (n >= N) continue;
            float v = acc[i][j];
            if (EPI == 0) {
                C[(size_t)m * N + n] = v;
            } else if (EPI == 1) {
                if (n < DINNER)
                    C[(size_t)m * DINNER + n] = v;
                else
                    C2[(size_t)m * DINNER + (n - DINNER)] = silu_f(v);
            } else {
                v = softplus_f(v + bias[n]);
                C[(size_t)m * N + n] = v;
            }
        }
    }
}

// causal depthwise conv (k=4) + bias + silu
__global__ __launch_bounds__(256) void conv_silu_kernel(
    const float* __restrict__ xin, const float* __restrict__ w,
    const float* __restrict__ bconv, float* __restrict__ xout) {
    int idx = blockIdx.x * 256 + threadIdx.x;
    if (idx >= BSZ * LSEQ * DINNER) return;
    int d = idx & (DINNER - 1);
    int bt = idx >> 11;
    int t = bt & (LSEQ - 1);
    float acc = bconv[d];
    const float* wr = &w[d * 4];
#pragma unroll
    for (int k = 0; k < 4; k++) {
        int tt = t + k - 3;
        if (tt >= 0) acc = fmaf(xin[idx + (k - 3) * DINNER], wr[k], acc);
    }
    xout[idx] = silu_f(acc);
}

// ---- chunked selective scan ----
// thread = (b, d, chunk); 16 states in registers; lane index = consecutive d
// pass1: from h=0, emit per-chunk (prod dA, h_end)   [layout ((b*NC+c)*DINNER+d)*16+s]
__global__ __launch_bounds__(256) void scan_pass1(
    const float* __restrict__ xb, const float* __restrict__ dt,
    const float* __restrict__ proj, const float* __restrict__ A_log,
    float* __restrict__ aprod, float* __restrict__ hend) {
    __shared__ float Bs[LC][DSTATE];
    const int tg = blockIdx.x * 256 + threadIdx.x;
    const int d = tg & (DINNER - 1);
    const int bc = tg >> 11;       // b*NC + c
    const int c = bc & (NC - 1);
    const int b = bc >> 5;         // / NC

    for (int idx = threadIdx.x; idx < LC * DSTATE; idx += 256) {
        int ti = idx >> 4, j = idx & 15;
        Bs[ti][j] = proj[(size_t)(b * LSEQ + c * LC + ti) * NPROJ + DTRANK + j];
    }
    __syncthreads();

    float Av[DSTATE], h[DSTATE], ap[DSTATE];
#pragma unroll
    for (int s = 0; s < DSTATE; s++) {
        Av[s] = -expf(A_log[d * DSTATE + s]);
        h[s] = 0.f;
        ap[s] = 1.f;
    }

    for (int i = 0; i < LC; i++) {
        size_t base = (size_t)(b * LSEQ + c * LC + i) * DINNER + d;
        float dtv = dt[base];
        float xv = xb[base];
        float dx = dtv * xv;
#pragma unroll
        for (int s = 0; s < DSTATE; s++) {
            float dA = __expf(dtv * Av[s]);
            ap[s] *= dA;
            h[s] = fmaf(dA, h[s], dx * Bs[i][s]);
        }
    }

    size_t o = ((size_t)bc * DINNER + d) * DSTATE;
#pragma unroll
    for (int q = 0; q < 4; q++) {
        *reinterpret_cast<float4*>(&aprod[o + q * 4]) =
            make_float4(ap[4 * q], ap[4 * q + 1], ap[4 * q + 2], ap[4 * q + 3]);
        *reinterpret_cast<float4*>(&hend[o + q * 4]) =
            make_float4(h[4 * q], h[4 * q + 1], h[4 * q + 2], h[4 * q + 3]);
    }
}

// pass2: serial combine over chunks; writes h_start IN PLACE over aprod
__global__ __launch_bounds__(256) void scan_pass2(
    float* __restrict__ aprod, const float* __restrict__ hend) {
    const int tg = blockIdx.x * 256 + threadIdx.x; // B*DINNER*DSTATE threads
    const int s = tg & (DSTATE - 1);
    const int d = (tg >> 4) & (DINNER - 1);
    const int b = tg >> 15;
    float h = 0.f;
    for (int c = 0; c < NC; c++) {
        size_t o = ((size_t)((b * NC + c) * DINNER) + d) * DSTATE + s;
        float a = aprod[o];
        float e = hend[o];
        aprod[o] = h; // h_start for this chunk
        h = fmaf(a, h, e);
    }
}

// pass3: rescan chunk from true h_start; y = (sum_s h*C + D*x) * silu(z),
// written in place over the silu(z) buffer (same thread, same address)
__global__ __launch_bounds__(256) void scan_pass3(
    const float* __restrict__ xb, const float* __restrict__ dt,
    const float* __restrict__ proj, const float* __restrict__ hstart,
    const float* __restrict__ A_log, const float* __restrict__ Dp,
    float* __restrict__ sz_y) {
    __shared__ float Bs[LC][DSTATE];
    __shared__ float Cs[LC][DSTATE];
    const int tg = blockIdx.x * 256 + threadIdx.x;
    const int d = tg & (DINNER - 1);
    const int bc = tg >> 11;
    const int c = bc & (NC - 1);
    const int b = bc >> 5;

    for (int idx = threadIdx.x; idx < LC * 2 * DSTATE; idx += 256) {
        int ti = idx >> 5, j = idx & 31;
        float v = proj[(size_t)(b * LSEQ + c * LC + ti) * NPROJ + DTRANK + j];
        if (j < DSTATE) Bs[ti][j] = v;
        else            Cs[ti][j - DSTATE] = v;
    }
    __syncthreads();

    float Av[DSTATE], h[DSTATE];
    size_t o = ((size_t)bc * DINNER + d) * DSTATE;
#pragma unroll
    for (int q = 0; q < 4; q++) {
        float4 hv = *reinterpret_cast<const float4*>(&hstart[o + q * 4]);
        h[4 * q] = hv.x; h[4 * q + 1] = hv.y; h[4 * q + 2] = hv.z; h[4 * q + 3] = hv.w;
    }
#pragma unroll
    for (int s = 0; s < DSTATE; s++)
        Av[s] = -expf(A_log[d * DSTATE + s]);
    const float Dd = Dp[d];

    for (int i = 0; i < LC; i++) {
        size_t base = (size_t)(b * LSEQ + c * LC + i) * DINNER + d;
        float dtv = dt[base];
        float xv = xb[base];
        float szv = sz_y[base];
        float dx = dtv * xv;
        float p = 0.f;
#pragma unroll
        for (int s = 0; s < DSTATE; s++) {
            float dA = __expf(dtv * Av[s]);
            h[s] = fmaf(dA, h[s], dx * Bs[i][s]);
            p = fmaf(h[s], Cs[i][s], p);
        }
        sz_y[base] = (p + Dd * xv) * szv;
    }
}

extern "C" void kernel_launch(void* const* d_in, const int* in_sizes, int n_in,
                              void* d_out, int out_size, void* d_ws,
                              size_t ws_size, hipStream_t stream) {
    const float* x = (const float*)d_in[0];
    const float* W_in = (const float*)d_in[1];
    const float* conv_w = (const float*)d_in[2];
    const float* conv_b = (const float*)d_in[3];
    const float* W_xproj = (const float*)d_in[4];
    const float* W_dt = (const float*)d_in[5];
    const float* b_dt = (const float*)d_in[6];
    const float* A_log = (const float*)d_in[7];
    const float* Dp = (const float*)d_in[8];
    const float* W_out = (const float*)d_in[9];
    float* out = (float*)d_out;

    char* ws = (char*)d_ws;
    const size_t SZ = (size_t)BSZ * LSEQ * DINNER * sizeof(float); // 32 MB
    float* xb_pre = (float*)(ws);           // dead after conv -> scan temps
    float* szbuf = (float*)(ws + SZ);       // silu(z), then y (in-place)
    float* xbbuf = (float*)(ws + 2 * SZ);   // post-conv xb
    float* dtbuf = (float*)(ws + 3 * SZ);   // dt
    float* projbuf = (float*)(ws + 4 * SZ); // proj (4096 x 96)
    // scan temps overlay xb_pre (2 x 8 MB needed, 32 MB available)
    float* aprod = (float*)(ws);            // then h_start in place
    float* hend = (float*)(ws + SZ / 2);

    const int M = BSZ * LSEQ; // 4096
    dim3 blk(256);

    // 1. xz = x @ W_in  (split: xb_pre | silu(z))
    gemm_kernel<1><<<dim3((2 * DINNER) / 64, M / 64), blk, 0, stream>>>(
        x, W_in, xb_pre, szbuf, nullptr, M, 2 * DINNER, DMODEL, DMODEL);

    // 2. conv + silu
    conv_silu_kernel<<<dim3((M * DINNER) / 256), blk, 0, stream>>>(
        xb_pre, conv_w, conv_b, xbbuf);

    // 3. proj = xb @ W_xproj  (N = 96)
    gemm_kernel<0><<<dim3(2, M / 64), blk, 0, stream>>>(
        xbbuf, W_xproj, projbuf, nullptr, nullptr, M, NPROJ, DINNER, DINNER);

    // 4. dt = softplus(proj[:, :64] @ W_dt + b_dt)
    gemm_kernel<2><<<dim3(DINNER / 64, M / 64), blk, 0, stream>>>(
        projbuf, W_dt, dtbuf, nullptr, b_dt, M, DINNER, DTRANK, NPROJ);

    // 5. chunked selective scan
    const int nthreads1 = BSZ * NC * DINNER; // 131072
    scan_pass1<<<dim3(nthreads1 / 256), blk, 0, stream>>>(
        xbbuf, dtbuf, projbuf, A_log, aprod, hend);
    const int nthreads2 = BSZ * DINNER * DSTATE; // 65536
    scan_pass2<<<dim3(nthreads2 / 256), blk, 0, stream>>>(aprod, hend);
    scan_pass3<<<dim3(nthreads1 / 256), blk, 0, stream>>>(
        xbbuf, dtbuf, projbuf, aprod, A_log, Dp, szbuf);

    // 6. out = y @ W_out   (y lives in szbuf now)
    gemm_kernel<0><<<dim3(DMODEL / 64, M / 64), blk, 0, stream>>>(
        szbuf, W_out, out, nullptr, nullptr, M, DMODEL, DINNER, DINNER);
}

// Round 3
// 475.272 us; speedup vs baseline: 4.7376x; 2.1328x over previous
//
#include <hip/hip_runtime.h>
#include <hip/hip_bf16.h>
#include <math.h>

#define BSZ 2
#define LSEQ 2048
#define DMODEL 1024
#define DSTATE 16
#define DCONV 4
#define DINNER 2048
#define DTRANK 64
#define NPROJ (DTRANK + 2 * DSTATE) // 96
#define NC 32   // scan chunks
#define LC 64   // steps per chunk

using short8 = __attribute__((ext_vector_type(8))) short;
using f32x4 = __attribute__((ext_vector_type(4))) float;
using u16x4 = __attribute__((ext_vector_type(4))) unsigned short;

__device__ __forceinline__ float silu_f(float v) {
    return v / (1.f + expf(-v));
}
__device__ __forceinline__ float softplus_f(float v) {
    return fmaxf(v, 0.f) + log1pf(expf(-fabsf(v)));
}
// fp32 -> bf16 bits, round-to-nearest-even
__device__ __forceinline__ unsigned short f2bf(float f) {
    unsigned u = __builtin_bit_cast(unsigned, f);
    u += 0x7fffu + ((u >> 16) & 1u);
    return (unsigned short)(u >> 16);
}

__device__ __forceinline__ void gld_lds16(const unsigned short* g, unsigned short* l) {
    __builtin_amdgcn_global_load_lds(
        (const __attribute__((address_space(1))) unsigned int*)g,
        (__attribute__((address_space(3))) unsigned int*)l, 16, 0, 0);
}

// ---- prep: fp32 -> bf16 (same layout), n4 = n/4 ----
__global__ __launch_bounds__(256) void f32_to_bf16_kernel(
    const float* __restrict__ in, unsigned short* __restrict__ out, int n4) {
    int i = blockIdx.x * 256 + threadIdx.x;
    if (i >= n4) return;
    float4 v = reinterpret_cast<const float4*>(in)[i];
    u16x4 o = {f2bf(v.x), f2bf(v.y), f2bf(v.z), f2bf(v.w)};
    reinterpret_cast<u16x4*>(out)[i] = o;
}

// ---- prep: transpose fp32 [R][Cc] -> bf16 [Cc][R] ----
__global__ __launch_bounds__(256) void transpose_bf16_kernel(
    const float* __restrict__ in, unsigned short* __restrict__ out, int R, int Cc) {
    __shared__ float t[32][33];
    const int tx = threadIdx.x & 31, ty = threadIdx.x >> 5; // 32 x 8
    const int c0 = blockIdx.x * 32, r0 = blockIdx.y * 32;
    for (int i = ty; i < 32; i += 8)
        t[i][tx] = in[(size_t)(r0 + i) * Cc + c0 + tx];
    __syncthreads();
    for (int i = ty; i < 32; i += 8)
        out[(size_t)(c0 + i) * R + r0 + tx] = f2bf(t[tx][i]);
}

// ---- bf16 MFMA GEMM: C[M,N] = A[M,K] @ Bt[N,K]^T ----
// 128x128 tile, 4 waves (2x2 of 64x64), BK=32, 16x16x32 bf16 MFMA.
// LDS layout [kg][row][8]: elem (row,k) at kg*1024 + row*8 + k%8, kg=k/8.
// EPI 0: plain fp32 store (ldc=N). EPI 1: n<DINNER -> C, else silu -> C2 (ldc=DINNER).
template <int EPI>
__global__ __launch_bounds__(256) void gemm_mfma(
    const unsigned short* __restrict__ A, const unsigned short* __restrict__ Bt,
    float* __restrict__ C, float* __restrict__ C2, int M, int N, int K) {
    __shared__ __align__(16) unsigned short As[4096];
    __shared__ __align__(16) unsigned short Bs[4096];
    const int tid = threadIdx.x;
    const int lane = tid & 63;
    const int wid = tid >> 6;
    const int wr = wid >> 1, wc = wid & 1;
    const int m0 = blockIdx.y * 128, n0 = blockIdx.x * 128;

    // staging slots: round r covers elements e = tid*8 + r*2048
    const int e0 = tid * 8;
    const int kg0 = e0 >> 10, row0 = (e0 >> 3) & 127;
    const int e1 = e0 + 2048;
    const int kg1 = e1 >> 10, row1 = (e1 >> 3) & 127;

    f32x4 acc[4][4];
#pragma unroll
    for (int m = 0; m < 4; m++)
#pragma unroll
        for (int n = 0; n < 4; n++) acc[m][n] = (f32x4){0.f, 0.f, 0.f, 0.f};

    const int fr = lane & 15;
    const int kg = lane >> 4;

    for (int k0 = 0; k0 < K; k0 += 32) {
        __syncthreads(); // previous iteration's reads complete
        gld_lds16(&A[(size_t)(m0 + row0) * K + k0 + kg0 * 8], &As[e0]);
        gld_lds16(&Bt[(size_t)(n0 + row0) * K + k0 + kg0 * 8], &Bs[e0]);
        gld_lds16(&A[(size_t)(m0 + row1) * K + k0 + kg1 * 8], &As[e1]);
        gld_lds16(&Bt[(size_t)(n0 + row1) * K + k0 + kg1 * 8], &Bs[e1]);
        __syncthreads(); // staging visible

        short8 a[4], b[4];
#pragma unroll
        for (int m = 0; m < 4; m++)
            a[m] = *reinterpret_cast<const short8*>(
                &As[kg * 1024 + (wr * 64 + m * 16 + fr) * 8]);
#pragma unroll
        for (int n = 0; n < 4; n++)
            b[n] = *reinterpret_cast<const short8*>(
                &Bs[kg * 1024 + (wc * 64 + n * 16 + fr) * 8]);
#pragma unroll
        for (int m = 0; m < 4; m++)
#pragma unroll
            for (int n = 0; n < 4; n++)
                acc[m][n] = __builtin_amdgcn_mfma_f32_16x16x32_bf16(
                    a[m], b[n], acc[m][n], 0, 0, 0);
    }

    const int g4 = (lane >> 4) * 4;
#pragma unroll
    for (int m = 0; m < 4; m++)
#pragma unroll
        for (int n = 0; n < 4; n++)
#pragma unroll
            for (int j = 0; j < 4; j++) {
                int mm = m0 + wr * 64 + m * 16 + g4 + j;
                int nn = n0 + wc * 64 + n * 16 + fr;
                float v = acc[m][n][j];
                if (EPI == 0) {
                    C[(size_t)mm * N + nn] = v;
                } else {
                    if (nn < DINNER)
                        C[(size_t)mm * DINNER + nn] = v;
                    else
                        C2[(size_t)mm * DINNER + (nn - DINNER)] = silu_f(v);
                }
            }
}

// ---- fp32 tiled GEMM (small/memory-bound cases) ----
// EPI 0: plain. EPI 2: softplus(v + bias[n])
template <int EPI>
__global__ __launch_bounds__(256) void gemm_kernel(
    const float* __restrict__ A, const float* __restrict__ B,
    float* __restrict__ C, const float* __restrict__ bias,
    int M, int N, int K, int lda) {
    __shared__ float As[16][68];
    __shared__ float Bs[16][64];

    const int tid = threadIdx.x;
    const int m0 = blockIdx.y * 64;
    const int n0 = blockIdx.x * 64;
    const int tx = tid & 15;
    const int ty = tid >> 4;
    const int arow = tid >> 2;
    const int ac4 = (tid & 3) * 4;
    const int bk = tid >> 4;
    const int bn4 = (tid & 15) * 4;

    float acc[4][4] = {};

    for (int k0 = 0; k0 < K; k0 += 16) {
        float4 av = *reinterpret_cast<const float4*>(
            &A[(size_t)(m0 + arow) * lda + k0 + ac4]);
        float4 bv;
        if (n0 + bn4 < N)
            bv = *reinterpret_cast<const float4*>(
                &B[(size_t)(k0 + bk) * N + n0 + bn4]);
        else
            bv = make_float4(0.f, 0.f, 0.f, 0.f);

        __syncthreads();
        As[ac4 + 0][arow] = av.x;
        As[ac4 + 1][arow] = av.y;
        As[ac4 + 2][arow] = av.z;
        As[ac4 + 3][arow] = av.w;
        *reinterpret_cast<float4*>(&Bs[bk][bn4]) = bv;
        __syncthreads();

#pragma unroll
        for (int kk = 0; kk < 16; kk++) {
            float4 a = *reinterpret_cast<const float4*>(&As[kk][ty * 4]);
            float4 b = *reinterpret_cast<const float4*>(&Bs[kk][tx * 4]);
            acc[0][0] = fmaf(a.x, b.x, acc[0][0]);
            acc[0][1] = fmaf(a.x, b.y, acc[0][1]);
            acc[0][2] = fmaf(a.x, b.z, acc[0][2]);
            acc[0][3] = fmaf(a.x, b.w, acc[0][3]);
            acc[1][0] = fmaf(a.y, b.x, acc[1][0]);
            acc[1][1] = fmaf(a.y, b.y, acc[1][1]);
            acc[1][2] = fmaf(a.y, b.z, acc[1][2]);
            acc[1][3] = fmaf(a.y, b.w, acc[1][3]);
            acc[2][0] = fmaf(a.z, b.x, acc[2][0]);
            acc[2][1] = fmaf(a.z, b.y, acc[2][1]);
            acc[2][2] = fmaf(a.z, b.z, acc[2][2]);
            acc[2][3] = fmaf(a.z, b.w, acc[2][3]);
            acc[3][0] = fmaf(a.w, b.x, acc[3][0]);
            acc[3][1] = fmaf(a.w, b.y, acc[3][1]);
            acc[3][2] = fmaf(a.w, b.z, acc[3][2]);
            acc[3][3] = fmaf(a.w, b.w, acc[3][3]);
        }
    }

#pragma unroll
    for (int i = 0; i < 4; i++) {
#pragma unroll
        for (int j = 0; j < 4; j++) {
            int m = m0 + ty * 4 + i;
            int n = n0 + tx * 4 + j;
            if (n >= N) continue;
            float v = acc[i][j];
            if (EPI == 2) v = softplus_f(v + bias[n]);
            C[(size_t)m * N + n] = v;
        }
    }
}

// causal depthwise conv (k=4) + bias + silu
__global__ __launch_bounds__(256) void conv_silu_kernel(
    const float* __restrict__ xin, const float* __restrict__ w,
    const float* __restrict__ bconv, float* __restrict__ xout) {
    int idx = blockIdx.x * 256 + threadIdx.x;
    if (idx >= BSZ * LSEQ * DINNER) return;
    int d = idx & (DINNER - 1);
    int bt = idx >> 11;
    int t = bt & (LSEQ - 1);
    float acc = bconv[d];
    const float* wr = &w[d * 4];
#pragma unroll
    for (int k = 0; k < 4; k++) {
        int tt = t + k - 3;
        if (tt >= 0) acc = fmaf(xin[idx + (k - 3) * DINNER], wr[k], acc);
    }
    xout[idx] = silu_f(acc);
}

// ---- chunked selective scan ----
__global__ __launch_bounds__(256) void scan_pass1(
    const float* __restrict__ xb, const float* __restrict__ dt,
    const float* __restrict__ proj, const float* __restrict__ A_log,
    float* __restrict__ aprod, float* __restrict__ hend) {
    __shared__ float Bs[LC][DSTATE];
    const int tg = blockIdx.x * 256 + threadIdx.x;
    const int d = tg & (DINNER - 1);
    const int bc = tg >> 11;
    const int c = bc & (NC - 1);
    const int b = bc >> 5;

    for (int idx = threadIdx.x; idx < LC * DSTATE; idx += 256) {
        int ti = idx >> 4, j = idx & 15;
        Bs[ti][j] = proj[(size_t)(b * LSEQ + c * LC + ti) * NPROJ + DTRANK + j];
    }
    __syncthreads();

    float Av[DSTATE], h[DSTATE], ap[DSTATE];
#pragma unroll
    for (int s = 0; s < DSTATE; s++) {
        Av[s] = -expf(A_log[d * DSTATE + s]);
        h[s] = 0.f;
        ap[s] = 1.f;
    }

    for (int i = 0; i < LC; i++) {
        size_t base = (size_t)(b * LSEQ + c * LC + i) * DINNER + d;
        float dtv = dt[base];
        float xv = xb[base];
        float dx = dtv * xv;
#pragma unroll
        for (int s = 0; s < DSTATE; s++) {
            float dA = __expf(dtv * Av[s]);
            ap[s] *= dA;
            h[s] = fmaf(dA, h[s], dx * Bs[i][s]);
        }
    }

    size_t o = ((size_t)bc * DINNER + d) * DSTATE;
#pragma unroll
    for (int q = 0; q < 4; q++) {
        *reinterpret_cast<float4*>(&aprod[o + q * 4]) =
            make_float4(ap[4 * q], ap[4 * q + 1], ap[4 * q + 2], ap[4 * q + 3]);
        *reinterpret_cast<float4*>(&hend[o + q * 4]) =
            make_float4(h[4 * q], h[4 * q + 1], h[4 * q + 2], h[4 * q + 3]);
    }
}

__global__ __launch_bounds__(256) void scan_pass2(
    float* __restrict__ aprod, const float* __restrict__ hend) {
    const int tg = blockIdx.x * 256 + threadIdx.x;
    const int s = tg & (DSTATE - 1);
    const int d = (tg >> 4) & (DINNER - 1);
    const int b = tg >> 15;
    float h = 0.f;
    for (int c = 0; c < NC; c++) {
        size_t o = ((size_t)((b * NC + c) * DINNER) + d) * DSTATE + s;
        float a = aprod[o];
        float e = hend[o];
        aprod[o] = h;
        h = fmaf(a, h, e);
    }
}

// pass3: rescan; y = (sum_s h*C + D*x) * silu(z) stored as bf16 for the out-GEMM
__global__ __launch_bounds__(256) void scan_pass3(
    const float* __restrict__ xb, const float* __restrict__ dt,
    const float* __restrict__ proj, const float* __restrict__ hstart,
    const float* __restrict__ A_log, const float* __restrict__ Dp,
    const float* __restrict__ sz, unsigned short* __restrict__ ybf) {
    __shared__ float Bs[LC][DSTATE];
    __shared__ float Cs[LC][DSTATE];
    const int tg = blockIdx.x * 256 + threadIdx.x;
    const int d = tg & (DINNER - 1);
    const int bc = tg >> 11;
    const int c = bc & (NC - 1);
    const int b = bc >> 5;

    for (int idx = threadIdx.x; idx < LC * 2 * DSTATE; idx += 256) {
        int ti = idx >> 5, j = idx & 31;
        float v = proj[(size_t)(b * LSEQ + c * LC + ti) * NPROJ + DTRANK + j];
        if (j < DSTATE) Bs[ti][j] = v;
        else            Cs[ti][j - DSTATE] = v;
    }
    __syncthreads();

    float Av[DSTATE], h[DSTATE];
    size_t o = ((size_t)bc * DINNER + d) * DSTATE;
#pragma unroll
    for (int q = 0; q < 4; q++) {
        float4 hv = *reinterpret_cast<const float4*>(&hstart[o + q * 4]);
        h[4 * q] = hv.x; h[4 * q + 1] = hv.y; h[4 * q + 2] = hv.z; h[4 * q + 3] = hv.w;
    }
#pragma unroll
    for (int s = 0; s < DSTATE; s++)
        Av[s] = -expf(A_log[d * DSTATE + s]);
    const float Dd = Dp[d];

    for (int i = 0; i < LC; i++) {
        size_t base = (size_t)(b * LSEQ + c * LC + i) * DINNER + d;
        float dtv = dt[base];
        float xv = xb[base];
        float szv = sz[base];
        float dx = dtv * xv;
        float p = 0.f;
#pragma unroll
        for (int s = 0; s < DSTATE; s++) {
            float dA = __expf(dtv * Av[s]);
            h[s] = fmaf(dA, h[s], dx * Bs[i][s]);
            p = fmaf(h[s], Cs[i][s], p);
        }
        ybf[base] = f2bf((p + Dd * xv) * szv);
    }
}

extern "C" void kernel_launch(void* const* d_in, const int* in_sizes, int n_in,
                              void* d_out, int out_size, void* d_ws,
                              size_t ws_size, hipStream_t stream) {
    const float* x = (const float*)d_in[0];
    const float* W_in = (const float*)d_in[1];
    const float* conv_w = (const float*)d_in[2];
    const float* conv_b = (const float*)d_in[3];
    const float* W_xproj = (const float*)d_in[4];
    const float* W_dt = (const float*)d_in[5];
    const float* b_dt = (const float*)d_in[6];
    const float* A_log = (const float*)d_in[7];
    const float* Dp = (const float*)d_in[8];
    const float* W_out = (const float*)d_in[9];
    float* out = (float*)d_out;

    char* ws = (char*)d_ws;
    const size_t SZ = (size_t)BSZ * LSEQ * DINNER * sizeof(float); // 32 MB
    float* xb_pre = (float*)(ws);            // [0,32M): GEMM1 out; later scan temps
    float* szbuf = (float*)(ws + SZ);        // silu(z)
    float* xbbuf = (float*)(ws + 2 * SZ);    // post-conv xb
    float* dtbuf = (float*)(ws + 3 * SZ);    // dt
    float* projbuf = (float*)(ws + 4 * SZ);  // 4096 x 96 fp32 (1.5 MB)
    unsigned short* WoutT = (unsigned short*)(ws + 4 * SZ + 0x200000); // 4 MB
    unsigned short* xbf   = (unsigned short*)(ws + 4 * SZ + 0x600000); // 8 MB
    unsigned short* WinT  = (unsigned short*)(ws + 4 * SZ + 0xE00000); // 8 MB
    // scan temps overlay xb_pre region after conv consumes it
    float* aprod = (float*)(ws);                       // 8 MB
    float* hend  = (float*)(ws + 0x800000);            // 8 MB
    unsigned short* ybf = (unsigned short*)(ws + 0x1000000); // 16 MB

    const int M = BSZ * LSEQ; // 4096
    dim3 blk(256);

    // prep: bf16 conversions / weight transposes
    f32_to_bf16_kernel<<<dim3((M * DMODEL / 4 + 255) / 256), blk, 0, stream>>>(
        x, xbf, M * DMODEL / 4);
    transpose_bf16_kernel<<<dim3(2 * DINNER / 32, DMODEL / 32), blk, 0, stream>>>(
        W_in, WinT, DMODEL, 2 * DINNER);
    transpose_bf16_kernel<<<dim3(DMODEL / 32, DINNER / 32), blk, 0, stream>>>(
        W_out, WoutT, DINNER, DMODEL);

    // 1. xz = x @ W_in (bf16 MFMA, split epilogue: xb_pre | silu -> szbuf)
    gemm_mfma<1><<<dim3((2 * DINNER) / 128, M / 128), blk, 0, stream>>>(
        xbf, WinT, xb_pre, szbuf, M, 2 * DINNER, DMODEL);

    // 2. conv + silu
    conv_silu_kernel<<<dim3((M * DINNER) / 256), blk, 0, stream>>>(
        xb_pre, conv_w, conv_b, xbbuf);

    // 3. proj = xb @ W_xproj (N = 96, fp32)
    gemm_kernel<0><<<dim3(2, M / 64), blk, 0, stream>>>(
        xbbuf, W_xproj, projbuf, nullptr, M, NPROJ, DINNER, DINNER);

    // 4. dt = softplus(proj[:, :64] @ W_dt + b_dt) (fp32)
    gemm_kernel<2><<<dim3(DINNER / 64, M / 64), blk, 0, stream>>>(
        projbuf, W_dt, dtbuf, b_dt, M, DINNER, DTRANK, NPROJ);

    // 5. chunked selective scan
    const int nthreads1 = BSZ * NC * DINNER;
    scan_pass1<<<dim3(nthreads1 / 256), blk, 0, stream>>>(
        xbbuf, dtbuf, projbuf, A_log, aprod, hend);
    const int nthreads2 = BSZ * DINNER * DSTATE;
    scan_pass2<<<dim3(nthreads2 / 256), blk, 0, stream>>>(aprod, hend);
    scan_pass3<<<dim3(nthreads1 / 256), blk, 0, stream>>>(
        xbbuf, dtbuf, projbuf, aprod, A_log, Dp, szbuf, ybf);

    // 6. out = y @ W_out (bf16 MFMA)
    gemm_mfma<0><<<dim3(DMODEL / 128, M / 128), blk, 0, stream>>>(
        ybf, WoutT, out, nullptr, M, DMODEL, DINNER);
}

// Round 4
// 382.085 us; speedup vs baseline: 5.8931x; 1.2439x over previous
//
#include <hip/hip_runtime.h>
#include <hip/hip_bf16.h>
#include <math.h>

#define BSZ 2
#define LSEQ 2048
#define DMODEL 1024
#define DSTATE 16
#define DCONV 4
#define DINNER 2048
#define DTRANK 64
#define NPROJ (DTRANK + 2 * DSTATE) // 96
#define NC 32   // scan chunks
#define LC 64   // steps per chunk
#define KS 8    // proj split-K chunks
#define KCH (DINNER / KS) // 256

using short8 = __attribute__((ext_vector_type(8))) short;
using f32x4 = __attribute__((ext_vector_type(4))) float;
using u16x4 = __attribute__((ext_vector_type(4))) unsigned short;

__device__ __forceinline__ float silu_f(float v) {
    return v / (1.f + expf(-v));
}
__device__ __forceinline__ float softplus_f(float v) {
    return fmaxf(v, 0.f) + log1pf(expf(-fabsf(v)));
}
// fp32 -> bf16 bits, round-to-nearest-even
__device__ __forceinline__ unsigned short f2bf(float f) {
    unsigned u = __builtin_bit_cast(unsigned, f);
    u += 0x7fffu + ((u >> 16) & 1u);
    return (unsigned short)(u >> 16);
}

__device__ __forceinline__ void gld_lds16(const unsigned short* g, unsigned short* l) {
    __builtin_amdgcn_global_load_lds(
        (const __attribute__((address_space(1))) unsigned int*)g,
        (__attribute__((address_space(3))) unsigned int*)l, 16, 0, 0);
}

// ---- prep: fp32 -> bf16 (same layout), n4 = n/4 ----
__global__ __launch_bounds__(256) void f32_to_bf16_kernel(
    const float* __restrict__ in, unsigned short* __restrict__ out, int n4) {
    int i = blockIdx.x * 256 + threadIdx.x;
    if (i >= n4) return;
    float4 v = reinterpret_cast<const float4*>(in)[i];
    u16x4 o = {f2bf(v.x), f2bf(v.y), f2bf(v.z), f2bf(v.w)};
    reinterpret_cast<u16x4*>(out)[i] = o;
}

// ---- prep: transpose fp32 [R][Cc] -> bf16 [Cc][R] ----
__global__ __launch_bounds__(256) void transpose_bf16_kernel(
    const float* __restrict__ in, unsigned short* __restrict__ out, int R, int Cc) {
    __shared__ float t[32][33];
    const int tx = threadIdx.x & 31, ty = threadIdx.x >> 5; // 32 x 8
    const int c0 = blockIdx.x * 32, r0 = blockIdx.y * 32;
    for (int i = ty; i < 32; i += 8)
        t[i][tx] = in[(size_t)(r0 + i) * Cc + c0 + tx];
    __syncthreads();
    for (int i = ty; i < 32; i += 8)
        out[(size_t)(c0 + i) * R + r0 + tx] = f2bf(t[tx][i]);
}

// ---- bf16 MFMA GEMM: C[M,N] = A[M,K] @ Bt[N,K]^T ----
// 128x128 tile, 4 waves (2x2 of 64x64), BK=32, 16x16x32 bf16 MFMA.
// EPI 0: plain fp32 store (ldc=N). EPI 1: n<DINNER -> C, else silu -> C2 (ldc=DINNER).
template <int EPI>
__global__ __launch_bounds__(256) void gemm_mfma(
    const unsigned short* __restrict__ A, const unsigned short* __restrict__ Bt,
    float* __restrict__ C, float* __restrict__ C2, int M, int N, int K) {
    __shared__ __align__(16) unsigned short As[4096];
    __shared__ __align__(16) unsigned short Bs[4096];
    const int tid = threadIdx.x;
    const int lane = tid & 63;
    const int wid = tid >> 6;
    const int wr = wid >> 1, wc = wid & 1;
    const int m0 = blockIdx.y * 128, n0 = blockIdx.x * 128;

    const int e0 = tid * 8;
    const int kg0 = e0 >> 10, row0 = (e0 >> 3) & 127;
    const int e1 = e0 + 2048;
    const int kg1 = e1 >> 10, row1 = (e1 >> 3) & 127;

    f32x4 acc[4][4];
#pragma unroll
    for (int m = 0; m < 4; m++)
#pragma unroll
        for (int n = 0; n < 4; n++) acc[m][n] = (f32x4){0.f, 0.f, 0.f, 0.f};

    const int fr = lane & 15;
    const int kg = lane >> 4;

    for (int k0 = 0; k0 < K; k0 += 32) {
        __syncthreads();
        gld_lds16(&A[(size_t)(m0 + row0) * K + k0 + kg0 * 8], &As[e0]);
        gld_lds16(&Bt[(size_t)(n0 + row0) * K + k0 + kg0 * 8], &Bs[e0]);
        gld_lds16(&A[(size_t)(m0 + row1) * K + k0 + kg1 * 8], &As[e1]);
        gld_lds16(&Bt[(size_t)(n0 + row1) * K + k0 + kg1 * 8], &Bs[e1]);
        __syncthreads();

        short8 a[4], b[4];
#pragma unroll
        for (int m = 0; m < 4; m++)
            a[m] = *reinterpret_cast<const short8*>(
                &As[kg * 1024 + (wr * 64 + m * 16 + fr) * 8]);
#pragma unroll
        for (int n = 0; n < 4; n++)
            b[n] = *reinterpret_cast<const short8*>(
                &Bs[kg * 1024 + (wc * 64 + n * 16 + fr) * 8]);
#pragma unroll
        for (int m = 0; m < 4; m++)
#pragma unroll
            for (int n = 0; n < 4; n++)
                acc[m][n] = __builtin_amdgcn_mfma_f32_16x16x32_bf16(
                    a[m], b[n], acc[m][n], 0, 0, 0);
    }

    const int g4 = (lane >> 4) * 4;
#pragma unroll
    for (int m = 0; m < 4; m++)
#pragma unroll
        for (int n = 0; n < 4; n++)
#pragma unroll
            for (int j = 0; j < 4; j++) {
                int mm = m0 + wr * 64 + m * 16 + g4 + j;
                int nn = n0 + wc * 64 + n * 16 + fr;
                float v = acc[m][n][j];
                if (EPI == 0) {
                    C[(size_t)mm * N + nn] = v;
                } else {
                    if (nn < DINNER)
                        C[(size_t)mm * DINNER + nn] = v;
                    else
                        C2[(size_t)mm * DINNER + (nn - DINNER)] = silu_f(v);
                }
            }
}

// ---- proj split-K MFMA: pp[kc][M][96] partial of xb_bf @ WxT^T ----
// grid (M/32, KS); 4 waves: mt = wid>>1 (m half), nh = wid&1 (n half of 96)
__global__ __launch_bounds__(256) void proj_splitk(
    const unsigned short* __restrict__ Abf,   // [M][DINNER] bf16
    const unsigned short* __restrict__ WxT,   // [NPROJ][DINNER] bf16
    float* __restrict__ pp) {
    const int lane = threadIdx.x & 63;
    const int wid = threadIdx.x >> 6;
    const int mt = wid >> 1;
    const int nh = wid & 1;
    const int m0 = blockIdx.x * 32;
    const int kc = blockIdx.y;
    const int fr = lane & 15;
    const int kg = lane >> 4;

    const size_t abase = (size_t)(m0 + mt * 16 + fr) * DINNER + kc * KCH + kg * 8;

    f32x4 acc[3];
#pragma unroll
    for (int i = 0; i < 3; i++) acc[i] = (f32x4){0.f, 0.f, 0.f, 0.f};

    for (int step = 0; step < KCH / 32; step++) {
        short8 a = *reinterpret_cast<const short8*>(&Abf[abase + step * 32]);
#pragma unroll
        for (int nt = 0; nt < 3; nt++) {
            int nrow = nh * 48 + nt * 16 + fr;
            short8 b = *reinterpret_cast<const short8*>(
                &WxT[(size_t)nrow * DINNER + kc * KCH + step * 32 + kg * 8]);
            acc[nt] = __builtin_amdgcn_mfma_f32_16x16x32_bf16(a, b, acc[nt], 0, 0, 0);
        }
    }
    const int g4 = (lane >> 4) * 4;
#pragma unroll
    for (int nt = 0; nt < 3; nt++)
#pragma unroll
        for (int j = 0; j < 4; j++) {
            int m = m0 + mt * 16 + g4 + j;
            int n = nh * 48 + nt * 16 + fr;
            pp[((size_t)kc * (BSZ * LSEQ) + m) * NPROJ + n] = acc[nt][j];
        }
}

__global__ __launch_bounds__(256) void proj_reduce(
    const float* __restrict__ pp, float* __restrict__ proj) {
    int i = blockIdx.x * 256 + threadIdx.x;
    if (i >= BSZ * LSEQ * NPROJ) return;
    float s = 0.f;
#pragma unroll
    for (int kc = 0; kc < KS; kc++)
        s += pp[(size_t)kc * BSZ * LSEQ * NPROJ + i];
    proj[i] = s;
}

// ---- fp32 tiled GEMM (dt path): EPI 2 = softplus(v + bias[n]) ----
template <int EPI>
__global__ __launch_bounds__(256) void gemm_kernel(
    const float* __restrict__ A, const float* __restrict__ B,
    float* __restrict__ C, const float* __restrict__ bias,
    int M, int N, int K, int lda) {
    __shared__ float As[16][68];
    __shared__ float Bs[16][64];

    const int tid = threadIdx.x;
    const int m0 = blockIdx.y * 64;
    const int n0 = blockIdx.x * 64;
    const int tx = tid & 15;
    const int ty = tid >> 4;
    const int arow = tid >> 2;
    const int ac4 = (tid & 3) * 4;
    const int bk = tid >> 4;
    const int bn4 = (tid & 15) * 4;

    float acc[4][4] = {};

    for (int k0 = 0; k0 < K; k0 += 16) {
        float4 av = *reinterpret_cast<const float4*>(
            &A[(size_t)(m0 + arow) * lda + k0 + ac4]);
        float4 bv = *reinterpret_cast<const float4*>(
            &B[(size_t)(k0 + bk) * N + n0 + bn4]);

        __syncthreads();
        As[ac4 + 0][arow] = av.x;
        As[ac4 + 1][arow] = av.y;
        As[ac4 + 2][arow] = av.z;
        As[ac4 + 3][arow] = av.w;
        *reinterpret_cast<float4*>(&Bs[bk][bn4]) = bv;
        __syncthreads();

#pragma unroll
        for (int kk = 0; kk < 16; kk++) {
            float4 a = *reinterpret_cast<const float4*>(&As[kk][ty * 4]);
            float4 b = *reinterpret_cast<const float4*>(&Bs[kk][tx * 4]);
            acc[0][0] = fmaf(a.x, b.x, acc[0][0]);
            acc[0][1] = fmaf(a.x, b.y, acc[0][1]);
            acc[0][2] = fmaf(a.x, b.z, acc[0][2]);
            acc[0][3] = fmaf(a.x, b.w, acc[0][3]);
            acc[1][0] = fmaf(a.y, b.x, acc[1][0]);
            acc[1][1] = fmaf(a.y, b.y, acc[1][1]);
            acc[1][2] = fmaf(a.y, b.z, acc[1][2]);
            acc[1][3] = fmaf(a.y, b.w, acc[1][3]);
            acc[2][0] = fmaf(a.z, b.x, acc[2][0]);
            acc[2][1] = fmaf(a.z, b.y, acc[2][1]);
            acc[2][2] = fmaf(a.z, b.z, acc[2][2]);
            acc[2][3] = fmaf(a.z, b.w, acc[2][3]);
            acc[3][0] = fmaf(a.w, b.x, acc[3][0]);
            acc[3][1] = fmaf(a.w, b.y, acc[3][1]);
            acc[3][2] = fmaf(a.w, b.z, acc[3][2]);
            acc[3][3] = fmaf(a.w, b.w, acc[3][3]);
        }
    }

#pragma unroll
    for (int i = 0; i < 4; i++) {
#pragma unroll
        for (int j = 0; j < 4; j++) {
            int m = m0 + ty * 4 + i;
            int n = n0 + tx * 4 + j;
            float v = acc[i][j];
            if (EPI == 2) v = softplus_f(v + bias[n]);
            C[(size_t)m * N + n] = v;
        }
    }
}

// causal depthwise conv (k=4) + bias + silu; writes fp32 (scan) + bf16 (proj)
__global__ __launch_bounds__(256) void conv_silu_kernel(
    const float* __restrict__ xin, const float* __restrict__ w,
    const float* __restrict__ bconv, float* __restrict__ xout,
    unsigned short* __restrict__ xout_bf) {
    int idx = blockIdx.x * 256 + threadIdx.x;
    if (idx >= BSZ * LSEQ * DINNER) return;
    int d = idx & (DINNER - 1);
    int bt = idx >> 11;
    int t = bt & (LSEQ - 1);
    float acc = bconv[d];
    const float* wr = &w[d * 4];
#pragma unroll
    for (int k = 0; k < 4; k++) {
        int tt = t + k - 3;
        if (tt >= 0) acc = fmaf(xin[idx + (k - 3) * DINNER], wr[k], acc);
    }
    float v = silu_f(acc);
    xout[idx] = v;
    xout_bf[idx] = f2bf(v);
}

// ---- chunked selective scan ----
__global__ __launch_bounds__(256) void scan_pass1(
    const float* __restrict__ xb, const float* __restrict__ dt,
    const float* __restrict__ proj, const float* __restrict__ A_log,
    float* __restrict__ aprod, float* __restrict__ hend) {
    __shared__ float Bs[LC][DSTATE];
    const int tg = blockIdx.x * 256 + threadIdx.x;
    const int d = tg & (DINNER - 1);
    const int bc = tg >> 11;
    const int c = bc & (NC - 1);
    const int b = bc >> 5;

    for (int idx = threadIdx.x; idx < LC * DSTATE; idx += 256) {
        int ti = idx >> 4, j = idx & 15;
        Bs[ti][j] = proj[(size_t)(b * LSEQ + c * LC + ti) * NPROJ + DTRANK + j];
    }
    __syncthreads();

    float Av[DSTATE], h[DSTATE], ap[DSTATE];
#pragma unroll
    for (int s = 0; s < DSTATE; s++) {
        Av[s] = -expf(A_log[d * DSTATE + s]);
        h[s] = 0.f;
        ap[s] = 1.f;
    }

    for (int i = 0; i < LC; i++) {
        size_t base = (size_t)(b * LSEQ + c * LC + i) * DINNER + d;
        float dtv = dt[base];
        float xv = xb[base];
        float dx = dtv * xv;
#pragma unroll
        for (int s = 0; s < DSTATE; s++) {
            float dA = __expf(dtv * Av[s]);
            ap[s] *= dA;
            h[s] = fmaf(dA, h[s], dx * Bs[i][s]);
        }
    }

    size_t o = ((size_t)bc * DINNER + d) * DSTATE;
#pragma unroll
    for (int q = 0; q < 4; q++) {
        *reinterpret_cast<float4*>(&aprod[o + q * 4]) =
            make_float4(ap[4 * q], ap[4 * q + 1], ap[4 * q + 2], ap[4 * q + 3]);
        *reinterpret_cast<float4*>(&hend[o + q * 4]) =
            make_float4(h[4 * q], h[4 * q + 1], h[4 * q + 2], h[4 * q + 3]);
    }
}

__global__ __launch_bounds__(256) void scan_pass2(
    float* __restrict__ aprod, const float* __restrict__ hend) {
    const int tg = blockIdx.x * 256 + threadIdx.x;
    const int s = tg & (DSTATE - 1);
    const int d = (tg >> 4) & (DINNER - 1);
    const int b = tg >> 15;
    float h = 0.f;
    for (int c = 0; c < NC; c++) {
        size_t o = ((size_t)((b * NC + c) * DINNER) + d) * DSTATE + s;
        float a = aprod[o];
        float e = hend[o];
        aprod[o] = h;
        h = fmaf(a, h, e);
    }
}

__global__ __launch_bounds__(256) void scan_pass3(
    const float* __restrict__ xb, const float* __restrict__ dt,
    const float* __restrict__ proj, const float* __restrict__ hstart,
    const float* __restrict__ A_log, const float* __restrict__ Dp,
    const float* __restrict__ sz, unsigned short* __restrict__ ybf) {
    __shared__ float Bs[LC][DSTATE];
    __shared__ float Cs[LC][DSTATE];
    const int tg = blockIdx.x * 256 + threadIdx.x;
    const int d = tg & (DINNER - 1);
    const int bc = tg >> 11;
    const int c = bc & (NC - 1);
    const int b = bc >> 5;

    for (int idx = threadIdx.x; idx < LC * 2 * DSTATE; idx += 256) {
        int ti = idx >> 5, j = idx & 31;
        float v = proj[(size_t)(b * LSEQ + c * LC + ti) * NPROJ + DTRANK + j];
        if (j < DSTATE) Bs[ti][j] = v;
        else            Cs[ti][j - DSTATE] = v;
    }
    __syncthreads();

    float Av[DSTATE], h[DSTATE];
    size_t o = ((size_t)bc * DINNER + d) * DSTATE;
#pragma unroll
    for (int q = 0; q < 4; q++) {
        float4 hv = *reinterpret_cast<const float4*>(&hstart[o + q * 4]);
        h[4 * q] = hv.x; h[4 * q + 1] = hv.y; h[4 * q + 2] = hv.z; h[4 * q + 3] = hv.w;
    }
#pragma unroll
    for (int s = 0; s < DSTATE; s++)
        Av[s] = -expf(A_log[d * DSTATE + s]);
    const float Dd = Dp[d];

    for (int i = 0; i < LC; i++) {
        size_t base = (size_t)(b * LSEQ + c * LC + i) * DINNER + d;
        float dtv = dt[base];
        float xv = xb[base];
        float szv = sz[base];
        float dx = dtv * xv;
        float p = 0.f;
#pragma unroll
        for (int s = 0; s < DSTATE; s++) {
            float dA = __expf(dtv * Av[s]);
            h[s] = fmaf(dA, h[s], dx * Bs[i][s]);
            p = fmaf(h[s], Cs[i][s], p);
        }
        ybf[base] = f2bf((p + Dd * xv) * szv);
    }
}

extern "C" void kernel_launch(void* const* d_in, const int* in_sizes, int n_in,
                              void* d_out, int out_size, void* d_ws,
                              size_t ws_size, hipStream_t stream) {
    const float* x = (const float*)d_in[0];
    const float* W_in = (const float*)d_in[1];
    const float* conv_w = (const float*)d_in[2];
    const float* conv_b = (const float*)d_in[3];
    const float* W_xproj = (const float*)d_in[4];
    const float* W_dt = (const float*)d_in[5];
    const float* b_dt = (const float*)d_in[6];
    const float* A_log = (const float*)d_in[7];
    const float* Dp = (const float*)d_in[8];
    const float* W_out = (const float*)d_in[9];
    float* out = (float*)d_out;

    char* ws = (char*)d_ws;
    const size_t SZ = (size_t)BSZ * LSEQ * DINNER * sizeof(float); // 32 MB
    float* xb_pre = (float*)(ws);            // [0,32M): GEMM1 out; later pp/scan temps
    float* szbuf = (float*)(ws + SZ);        // silu(z)
    float* xbbuf = (float*)(ws + 2 * SZ);    // post-conv xb fp32
    float* dtbuf = (float*)(ws + 3 * SZ);    // dt (after xbf16 is dead)
    float* projbuf = (float*)(ws + 4 * SZ);  // 4096 x 96 fp32 (1.5 MB)
    unsigned short* WoutT = (unsigned short*)(ws + 4 * SZ + 0x200000); // 4 MB
    unsigned short* xbf   = (unsigned short*)(ws + 4 * SZ + 0x600000); // 8 MB
    unsigned short* WinT  = (unsigned short*)(ws + 4 * SZ + 0xE00000); // 8 MB
    unsigned short* WxT   = (unsigned short*)(ws + 4 * SZ + 0x1600000); // 384 KB
    // overlays
    float* pp    = (float*)(ws);                        // 12.6 MB (pre-scan)
    float* aprod = (float*)(ws);                        // 8 MB
    float* hend  = (float*)(ws + 0x800000);             // 8 MB
    unsigned short* ybf = (unsigned short*)(ws + 0x1000000);      // 16 MB
    unsigned short* xbf16 = (unsigned short*)(ws + 3 * SZ);       // 16 MB (dies before dt write)

    const int M = BSZ * LSEQ; // 4096
    dim3 blk(256);

    // prep: bf16 conversions / weight transposes
    f32_to_bf16_kernel<<<dim3((M * DMODEL / 4 + 255) / 256), blk, 0, stream>>>(
        x, xbf, M * DMODEL / 4);
    transpose_bf16_kernel<<<dim3(2 * DINNER / 32, DMODEL / 32), blk, 0, stream>>>(
        W_in, WinT, DMODEL, 2 * DINNER);
    transpose_bf16_kernel<<<dim3(DMODEL / 32, DINNER / 32), blk, 0, stream>>>(
        W_out, WoutT, DINNER, DMODEL);
    transpose_bf16_kernel<<<dim3(NPROJ / 32, DINNER / 32), blk, 0, stream>>>(
        W_xproj, WxT, DINNER, NPROJ);

    // 1. xz = x @ W_in (bf16 MFMA, split epilogue: xb_pre | silu -> szbuf)
    gemm_mfma<1><<<dim3((2 * DINNER) / 128, M / 128), blk, 0, stream>>>(
        xbf, WinT, xb_pre, szbuf, M, 2 * DINNER, DMODEL);

    // 2. conv + silu (fp32 + bf16 outputs)
    conv_silu_kernel<<<dim3((M * DINNER) / 256), blk, 0, stream>>>(
        xb_pre, conv_w, conv_b, xbbuf, xbf16);

    // 3. proj = xb @ W_xproj via split-K MFMA + reduce
    proj_splitk<<<dim3(M / 32, KS), blk, 0, stream>>>(xbf16, WxT, pp);
    proj_reduce<<<dim3((M * NPROJ) / 256), blk, 0, stream>>>(pp, projbuf);

    // 4. dt = softplus(proj[:, :64] @ W_dt + b_dt) (fp32)
    gemm_kernel<2><<<dim3(DINNER / 64, M / 64), blk, 0, stream>>>(
        projbuf, W_dt, dtbuf, b_dt, M, DINNER, DTRANK, NPROJ);

    // 5. chunked selective scan
    const int nthreads1 = BSZ * NC * DINNER;
    scan_pass1<<<dim3(nthreads1 / 256), blk, 0, stream>>>(
        xbbuf, dtbuf, projbuf, A_log, aprod, hend);
    const int nthreads2 = BSZ * DINNER * DSTATE;
    scan_pass2<<<dim3(nthreads2 / 256), blk, 0, stream>>>(aprod, hend);
    scan_pass3<<<dim3(nthreads1 / 256), blk, 0, stream>>>(
        xbbuf, dtbuf, projbuf, aprod, A_log, Dp, szbuf, ybf);

    // 6. out = y @ W_out (bf16 MFMA)
    gemm_mfma<0><<<dim3(DMODEL / 128, M / 128), blk, 0, stream>>>(
        ybf, WoutT, out, nullptr, M, DMODEL, DINNER);
}

// Round 5
// 365.246 us; speedup vs baseline: 6.1648x; 1.0461x over previous
//
#include <hip/hip_runtime.h>
#include <hip/hip_bf16.h>
#include <math.h>

#define BSZ 2
#define LSEQ 2048
#define DMODEL 1024
#define DSTATE 16
#define DCONV 4
#define DINNER 2048
#define DTRANK 64
#define NPROJ (DTRANK + 2 * DSTATE) // 96
#define NC 32   // scan chunks
#define LC 64   // steps per chunk
#define KS 8    // proj split-K chunks
#define KCH (DINNER / KS) // 256

using short8 = __attribute__((ext_vector_type(8))) short;
using f32x4 = __attribute__((ext_vector_type(4))) float;
using u16x4 = __attribute__((ext_vector_type(4))) unsigned short;

__device__ __forceinline__ float silu_f(float v) {
    return v / (1.f + expf(-v));
}
__device__ __forceinline__ float softplus_f(float v) {
    return fmaxf(v, 0.f) + log1pf(expf(-fabsf(v)));
}
// fp32 -> bf16 bits, round-to-nearest-even
__device__ __forceinline__ unsigned short f2bf(float f) {
    unsigned u = __builtin_bit_cast(unsigned, f);
    u += 0x7fffu + ((u >> 16) & 1u);
    return (unsigned short)(u >> 16);
}
__device__ __forceinline__ float bf2f(unsigned short u) {
    unsigned x = ((unsigned)u) << 16;
    return __builtin_bit_cast(float, x);
}

__device__ __forceinline__ void gld_lds16(const unsigned short* g, unsigned short* l) {
    __builtin_amdgcn_global_load_lds(
        (const __attribute__((address_space(1))) unsigned int*)g,
        (__attribute__((address_space(3))) unsigned int*)l, 16, 0, 0);
}

// ---- prep: fp32 -> bf16 (same layout), n4 = n/4 ----
__global__ __launch_bounds__(256) void f32_to_bf16_kernel(
    const float* __restrict__ in, unsigned short* __restrict__ out, int n4) {
    int i = blockIdx.x * 256 + threadIdx.x;
    if (i >= n4) return;
    float4 v = reinterpret_cast<const float4*>(in)[i];
    u16x4 o = {f2bf(v.x), f2bf(v.y), f2bf(v.z), f2bf(v.w)};
    reinterpret_cast<u16x4*>(out)[i] = o;
}

// ---- prep: transpose fp32 [R][Cc] -> bf16 [Cc][R] ----
__global__ __launch_bounds__(256) void transpose_bf16_kernel(
    const float* __restrict__ in, unsigned short* __restrict__ out, int R, int Cc) {
    __shared__ float t[32][33];
    const int tx = threadIdx.x & 31, ty = threadIdx.x >> 5; // 32 x 8
    const int c0 = blockIdx.x * 32, r0 = blockIdx.y * 32;
    for (int i = ty; i < 32; i += 8)
        t[i][tx] = in[(size_t)(r0 + i) * Cc + c0 + tx];
    __syncthreads();
    for (int i = ty; i < 32; i += 8)
        out[(size_t)(c0 + i) * R + r0 + tx] = f2bf(t[tx][i]);
}

// ---- bf16 MFMA GEMM: C[M,N] = A[M,K] @ Bt[N,K]^T ----
// 128x128 tile, 4 waves (2x2 of 64x64), BK=32, double-buffered LDS prefetch.
// EPI 0: plain store. EPI 1: n<DINNER -> C, else silu -> C2 (ldc=DINNER).
// EPI 2: softplus(v + bias[n]). CT = float | unsigned short (bf16).
template <int EPI, typename CT>
__global__ __launch_bounds__(256) void gemm_mfma(
    const unsigned short* __restrict__ A, const unsigned short* __restrict__ Bt,
    CT* __restrict__ C, CT* __restrict__ C2, const float* __restrict__ bias,
    int M, int N, int K) {
    __shared__ __align__(16) unsigned short As[2][4096];
    __shared__ __align__(16) unsigned short Bs[2][4096];
    const int tid = threadIdx.x;
    const int lane = tid & 63;
    const int wid = tid >> 6;
    const int wr = wid >> 1, wc = wid & 1;
    const int m0 = blockIdx.y * 128, n0 = blockIdx.x * 128;

    // staging slots: LDS layout [kg][row][8]; linear in tid for global_load_lds
    const int e0 = tid * 8;
    const int kg0 = e0 >> 10, row0 = (e0 >> 3) & 127;
    const int e1 = e0 + 2048;
    const int kg1 = e1 >> 10, row1 = (e1 >> 3) & 127;

    f32x4 acc[4][4];
#pragma unroll
    for (int m = 0; m < 4; m++)
#pragma unroll
        for (int n = 0; n < 4; n++) acc[m][n] = (f32x4){0.f, 0.f, 0.f, 0.f};

    const int fr = lane & 15;
    const int kg = lane >> 4;
    const int nt = K / 32;

    // prologue: stage tile 0 into buffer 0
    gld_lds16(&A[(size_t)(m0 + row0) * K + kg0 * 8], &As[0][e0]);
    gld_lds16(&Bt[(size_t)(n0 + row0) * K + kg0 * 8], &Bs[0][e0]);
    gld_lds16(&A[(size_t)(m0 + row1) * K + kg1 * 8], &As[0][e1]);
    gld_lds16(&Bt[(size_t)(n0 + row1) * K + kg1 * 8], &Bs[0][e1]);
    __syncthreads();

    int cur = 0;
    for (int t = 0; t < nt; t++) {
        if (t + 1 < nt) { // issue next-tile prefetch BEFORE compute
            const int k0 = (t + 1) * 32;
            gld_lds16(&A[(size_t)(m0 + row0) * K + k0 + kg0 * 8], &As[cur ^ 1][e0]);
            gld_lds16(&Bt[(size_t)(n0 + row0) * K + k0 + kg0 * 8], &Bs[cur ^ 1][e0]);
            gld_lds16(&A[(size_t)(m0 + row1) * K + k0 + kg1 * 8], &As[cur ^ 1][e1]);
            gld_lds16(&Bt[(size_t)(n0 + row1) * K + k0 + kg1 * 8], &Bs[cur ^ 1][e1]);
        }
        short8 a[4], b[4];
#pragma unroll
        for (int m = 0; m < 4; m++)
            a[m] = *reinterpret_cast<const short8*>(
                &As[cur][kg * 1024 + (wr * 64 + m * 16 + fr) * 8]);
#pragma unroll
        for (int n = 0; n < 4; n++)
            b[n] = *reinterpret_cast<const short8*>(
                &Bs[cur][kg * 1024 + (wc * 64 + n * 16 + fr) * 8]);
#pragma unroll
        for (int m = 0; m < 4; m++)
#pragma unroll
            for (int n = 0; n < 4; n++)
                acc[m][n] = __builtin_amdgcn_mfma_f32_16x16x32_bf16(
                    a[m], b[n], acc[m][n], 0, 0, 0);
        __syncthreads(); // drains vmcnt (prefetch landed) + all reads of cur done
        cur ^= 1;
    }

    const int g4 = (lane >> 4) * 4;
#pragma unroll
    for (int m = 0; m < 4; m++)
#pragma unroll
        for (int n = 0; n < 4; n++)
#pragma unroll
            for (int j = 0; j < 4; j++) {
                int mm = m0 + wr * 64 + m * 16 + g4 + j;
                int nn = n0 + wc * 64 + n * 16 + fr;
                float v = acc[m][n][j];
                if (EPI == 2) v = softplus_f(v + bias[nn]);
                if (EPI == 1) {
                    if (nn < DINNER) {
                        if constexpr (sizeof(CT) == 2)
                            C[(size_t)mm * DINNER + nn] = f2bf(v);
                        else
                            C[(size_t)mm * DINNER + nn] = v;
                    } else {
                        float sv = silu_f(v);
                        if constexpr (sizeof(CT) == 2)
                            C2[(size_t)mm * DINNER + (nn - DINNER)] = f2bf(sv);
                        else
                            C2[(size_t)mm * DINNER + (nn - DINNER)] = sv;
                    }
                } else {
                    if constexpr (sizeof(CT) == 2)
                        C[(size_t)mm * N + nn] = f2bf(v);
                    else
                        C[(size_t)mm * N + nn] = v;
                }
            }
}

// ---- proj split-K MFMA: pp[kc][M][96] partial of xb_bf @ WxT^T ----
__global__ __launch_bounds__(256) void proj_splitk(
    const unsigned short* __restrict__ Abf,   // [M][DINNER] bf16
    const unsigned short* __restrict__ WxT,   // [NPROJ][DINNER] bf16
    float* __restrict__ pp) {
    const int lane = threadIdx.x & 63;
    const int wid = threadIdx.x >> 6;
    const int mt = wid >> 1;
    const int nh = wid & 1;
    const int m0 = blockIdx.x * 32;
    const int kc = blockIdx.y;
    const int fr = lane & 15;
    const int kg = lane >> 4;

    const size_t abase = (size_t)(m0 + mt * 16 + fr) * DINNER + kc * KCH + kg * 8;

    f32x4 acc[3];
#pragma unroll
    for (int i = 0; i < 3; i++) acc[i] = (f32x4){0.f, 0.f, 0.f, 0.f};

    for (int step = 0; step < KCH / 32; step++) {
        short8 a = *reinterpret_cast<const short8*>(&Abf[abase + step * 32]);
#pragma unroll
        for (int nt = 0; nt < 3; nt++) {
            int nrow = nh * 48 + nt * 16 + fr;
            short8 b = *reinterpret_cast<const short8*>(
                &WxT[(size_t)nrow * DINNER + kc * KCH + step * 32 + kg * 8]);
            acc[nt] = __builtin_amdgcn_mfma_f32_16x16x32_bf16(a, b, acc[nt], 0, 0, 0);
        }
    }
    const int g4 = (lane >> 4) * 4;
#pragma unroll
    for (int nt = 0; nt < 3; nt++)
#pragma unroll
        for (int j = 0; j < 4; j++) {
            int m = m0 + mt * 16 + g4 + j;
            int n = nh * 48 + nt * 16 + fr;
            pp[((size_t)kc * (BSZ * LSEQ) + m) * NPROJ + n] = acc[nt][j];
        }
}

// reduce split-K partials; emit fp32 proj + bf16 dt_in (cols < DTRANK)
__global__ __launch_bounds__(256) void proj_reduce(
    const float* __restrict__ pp, float* __restrict__ proj,
    unsigned short* __restrict__ dtin) {
    int i = blockIdx.x * 256 + threadIdx.x;
    if (i >= BSZ * LSEQ * NPROJ) return;
    float s = 0.f;
#pragma unroll
    for (int kc = 0; kc < KS; kc++)
        s += pp[(size_t)kc * BSZ * LSEQ * NPROJ + i];
    proj[i] = s;
    int m = i / NPROJ;
    int n = i - m * NPROJ;
    if (n < DTRANK) dtin[(size_t)m * DTRANK + n] = f2bf(s);
}

// causal depthwise conv (k=4) + bias + silu; bf16 in, bf16 out
__global__ __launch_bounds__(256) void conv_silu_kernel(
    const unsigned short* __restrict__ xin, const float* __restrict__ w,
    const float* __restrict__ bconv, unsigned short* __restrict__ xout) {
    int idx = blockIdx.x * 256 + threadIdx.x;
    if (idx >= BSZ * LSEQ * DINNER) return;
    int d = idx & (DINNER - 1);
    int bt = idx >> 11;
    int t = bt & (LSEQ - 1);
    float acc = bconv[d];
    const float* wr = &w[d * 4];
#pragma unroll
    for (int k = 0; k < 4; k++) {
        int tt = t + k - 3;
        if (tt >= 0) acc = fmaf(bf2f(xin[idx + (k - 3) * DINNER]), wr[k], acc);
    }
    xout[idx] = f2bf(silu_f(acc));
}

// ---- chunked selective scan (bf16 operands, fp32 state) ----
__global__ __launch_bounds__(256) void scan_pass1(
    const unsigned short* __restrict__ xb, const unsigned short* __restrict__ dt,
    const float* __restrict__ proj, const float* __restrict__ A_log,
    float* __restrict__ aprod, float* __restrict__ hend) {
    __shared__ float Bs[LC][DSTATE];
    const int tg = blockIdx.x * 256 + threadIdx.x;
    const int d = tg & (DINNER - 1);
    const int bc = tg >> 11;
    const int c = bc & (NC - 1);
    const int b = bc >> 5;

    for (int idx = threadIdx.x; idx < LC * DSTATE; idx += 256) {
        int ti = idx >> 4, j = idx & 15;
        Bs[ti][j] = proj[(size_t)(b * LSEQ + c * LC + ti) * NPROJ + DTRANK + j];
    }
    __syncthreads();

    float Av[DSTATE], h[DSTATE], ap[DSTATE];
#pragma unroll
    for (int s = 0; s < DSTATE; s++) {
        Av[s] = -expf(A_log[d * DSTATE + s]);
        h[s] = 0.f;
        ap[s] = 1.f;
    }

    for (int i = 0; i < LC; i++) {
        size_t base = (size_t)(b * LSEQ + c * LC + i) * DINNER + d;
        float dtv = bf2f(dt[base]);
        float xv = bf2f(xb[base]);
        float dx = dtv * xv;
#pragma unroll
        for (int s = 0; s < DSTATE; s++) {
            float dA = __expf(dtv * Av[s]);
            ap[s] *= dA;
            h[s] = fmaf(dA, h[s], dx * Bs[i][s]);
        }
    }

    size_t o = ((size_t)bc * DINNER + d) * DSTATE;
#pragma unroll
    for (int q = 0; q < 4; q++) {
        *reinterpret_cast<float4*>(&aprod[o + q * 4]) =
            make_float4(ap[4 * q], ap[4 * q + 1], ap[4 * q + 2], ap[4 * q + 3]);
        *reinterpret_cast<float4*>(&hend[o + q * 4]) =
            make_float4(h[4 * q], h[4 * q + 1], h[4 * q + 2], h[4 * q + 3]);
    }
}

__global__ __launch_bounds__(256) void scan_pass2(
    float* __restrict__ aprod, const float* __restrict__ hend) {
    const int tg = blockIdx.x * 256 + threadIdx.x;
    const int s = tg & (DSTATE - 1);
    const int d = (tg >> 4) & (DINNER - 1);
    const int b = tg >> 15;
    float h = 0.f;
    for (int c = 0; c < NC; c++) {
        size_t o = ((size_t)((b * NC + c) * DINNER) + d) * DSTATE + s;
        float a = aprod[o];
        float e = hend[o];
        aprod[o] = h;
        h = fmaf(a, h, e);
    }
}

__global__ __launch_bounds__(256) void scan_pass3(
    const unsigned short* __restrict__ xb, const unsigned short* __restrict__ dt,
    const float* __restrict__ proj, const float* __restrict__ hstart,
    const float* __restrict__ A_log, const float* __restrict__ Dp,
    const unsigned short* __restrict__ sz, unsigned short* __restrict__ ybf) {
    __shared__ float Bs[LC][DSTATE];
    __shared__ float Cs[LC][DSTATE];
    const int tg = blockIdx.x * 256 + threadIdx.x;
    const int d = tg & (DINNER - 1);
    const int bc = tg >> 11;
    const int c = bc & (NC - 1);
    const int b = bc >> 5;

    for (int idx = threadIdx.x; idx < LC * 2 * DSTATE; idx += 256) {
        int ti = idx >> 5, j = idx & 31;
        float v = proj[(size_t)(b * LSEQ + c * LC + ti) * NPROJ + DTRANK + j];
        if (j < DSTATE) Bs[ti][j] = v;
        else            Cs[ti][j - DSTATE] = v;
    }
    __syncthreads();

    float Av[DSTATE], h[DSTATE];
    size_t o = ((size_t)bc * DINNER + d) * DSTATE;
#pragma unroll
    for (int q = 0; q < 4; q++) {
        float4 hv = *reinterpret_cast<const float4*>(&hstart[o + q * 4]);
        h[4 * q] = hv.x; h[4 * q + 1] = hv.y; h[4 * q + 2] = hv.z; h[4 * q + 3] = hv.w;
    }
#pragma unroll
    for (int s = 0; s < DSTATE; s++)
        Av[s] = -expf(A_log[d * DSTATE + s]);
    const float Dd = Dp[d];

    for (int i = 0; i < LC; i++) {
        size_t base = (size_t)(b * LSEQ + c * LC + i) * DINNER + d;
        float dtv = bf2f(dt[base]);
        float xv = bf2f(xb[base]);
        float szv = bf2f(sz[base]);
        float dx = dtv * xv;
        float p = 0.f;
#pragma unroll
        for (int s = 0; s < DSTATE; s++) {
            float dA = __expf(dtv * Av[s]);
            h[s] = fmaf(dA, h[s], dx * Bs[i][s]);
            p = fmaf(h[s], Cs[i][s], p);
        }
        ybf[base] = f2bf((p + Dd * xv) * szv);
    }
}

extern "C" void kernel_launch(void* const* d_in, const int* in_sizes, int n_in,
                              void* d_out, int out_size, void* d_ws,
                              size_t ws_size, hipStream_t stream) {
    const float* x = (const float*)d_in[0];
    const float* W_in = (const float*)d_in[1];
    const float* conv_w = (const float*)d_in[2];
    const float* conv_b = (const float*)d_in[3];
    const float* W_xproj = (const float*)d_in[4];
    const float* W_dt = (const float*)d_in[5];
    const float* b_dt = (const float*)d_in[6];
    const float* A_log = (const float*)d_in[7];
    const float* Dp = (const float*)d_in[8];
    const float* W_out = (const float*)d_in[9];
    float* out = (float*)d_out;

    char* ws = (char*)d_ws;
    const size_t MB = 1u << 20;
    // [0,16M): pp (12.6M) -> later aprod(8M)+hend(8M)
    float* pp    = (float*)(ws);
    float* aprod = (float*)(ws);
    float* hend  = (float*)(ws + 8 * MB);
    unsigned short* xbpre_bf = (unsigned short*)(ws + 16 * MB);  // 16 MB
    unsigned short* sz_bf    = (unsigned short*)(ws + 32 * MB);  // 16 MB
    unsigned short* xb_bf    = (unsigned short*)(ws + 48 * MB);  // 16 MB
    unsigned short* dt_bf    = (unsigned short*)(ws + 64 * MB);  // 16 MB
    unsigned short* ybf      = (unsigned short*)(ws + 80 * MB);  // 8 MB
    float* projbuf           = (float*)(ws + 88 * MB);           // 1.5 MB
    unsigned short* dtin_bf  = (unsigned short*)(ws + 90 * MB);  // 0.5 MB
    unsigned short* xbf      = (unsigned short*)(ws + 91 * MB);  // 8 MB
    unsigned short* WinT     = (unsigned short*)(ws + 99 * MB);  // 8 MB
    unsigned short* WoutT    = (unsigned short*)(ws + 107 * MB); // 4 MB
    unsigned short* WxT      = (unsigned short*)(ws + 111 * MB); // 384 KB
    unsigned short* WdtT     = (unsigned short*)(ws + 112 * MB); // 256 KB

    const int M = BSZ * LSEQ; // 4096
    dim3 blk(256);

    // prep: bf16 conversions / weight transposes
    f32_to_bf16_kernel<<<dim3((M * DMODEL / 4 + 255) / 256), blk, 0, stream>>>(
        x, xbf, M * DMODEL / 4);
    transpose_bf16_kernel<<<dim3(2 * DINNER / 32, DMODEL / 32), blk, 0, stream>>>(
        W_in, WinT, DMODEL, 2 * DINNER);
    transpose_bf16_kernel<<<dim3(DMODEL / 32, DINNER / 32), blk, 0, stream>>>(
        W_out, WoutT, DINNER, DMODEL);
    transpose_bf16_kernel<<<dim3(NPROJ / 32, DINNER / 32), blk, 0, stream>>>(
        W_xproj, WxT, DINNER, NPROJ);
    transpose_bf16_kernel<<<dim3(DINNER / 32, DTRANK / 32), blk, 0, stream>>>(
        W_dt, WdtT, DTRANK, DINNER);

    // 1. xz = x @ W_in (bf16 MFMA, split: xbpre_bf | silu -> sz_bf)
    gemm_mfma<1, unsigned short><<<dim3((2 * DINNER) / 128, M / 128), blk, 0, stream>>>(
        xbf, WinT, xbpre_bf, sz_bf, nullptr, M, 2 * DINNER, DMODEL);

    // 2. conv + silu (bf16 -> bf16)
    conv_silu_kernel<<<dim3((M * DINNER) / 256), blk, 0, stream>>>(
        xbpre_bf, conv_w, conv_b, xb_bf);

    // 3. proj = xb @ W_xproj via split-K MFMA + reduce (emits fp32 proj + bf16 dt_in)
    proj_splitk<<<dim3(M / 32, KS), blk, 0, stream>>>(xb_bf, WxT, pp);
    proj_reduce<<<dim3((M * NPROJ) / 256), blk, 0, stream>>>(pp, projbuf, dtin_bf);

    // 4. dt = softplus(dt_in @ W_dt + b_dt) (bf16 MFMA, K=64)
    gemm_mfma<2, unsigned short><<<dim3(DINNER / 128, M / 128), blk, 0, stream>>>(
        dtin_bf, WdtT, dt_bf, nullptr, b_dt, M, DINNER, DTRANK);

    // 5. chunked selective scan
    const int nthreads1 = BSZ * NC * DINNER;
    scan_pass1<<<dim3(nthreads1 / 256), blk, 0, stream>>>(
        xb_bf, dt_bf, projbuf, A_log, aprod, hend);
    const int nthreads2 = BSZ * DINNER * DSTATE;
    scan_pass2<<<dim3(nthreads2 / 256), blk, 0, stream>>>(aprod, hend);
    scan_pass3<<<dim3(nthreads1 / 256), blk, 0, stream>>>(
        xb_bf, dt_bf, projbuf, aprod, A_log, Dp, sz_bf, ybf);

    // 6. out = y @ W_out (bf16 MFMA, fp32 store)
    gemm_mfma<0, float><<<dim3(DMODEL / 128, M / 128), blk, 0, stream>>>(
        ybf, WoutT, out, nullptr, nullptr, M, DMODEL, DINNER);
}

// Round 6
// 314.782 us; speedup vs baseline: 7.1531x; 1.1603x over previous
//
#include <hip/hip_runtime.h>
#include <hip/hip_bf16.h>
#include <math.h>

#define BSZ 2
#define LSEQ 2048
#define DMODEL 1024
#define DSTATE 16
#define DCONV 4
#define DINNER 2048
#define DTRANK 64
#define NPROJ (DTRANK + 2 * DSTATE) // 96
#define NC 32   // scan chunks
#define LC 64   // steps per chunk
#define KS 8    // proj split-K chunks
#define KCH (DINNER / KS) // 256

using short8 = __attribute__((ext_vector_type(8))) short;
using f32x4 = __attribute__((ext_vector_type(4))) float;
using u16x4 = __attribute__((ext_vector_type(4))) unsigned short;

__device__ __forceinline__ float silu_f(float v) {
    return v / (1.f + expf(-v));
}
__device__ __forceinline__ float softplus_f(float v) {
    return fmaxf(v, 0.f) + log1pf(expf(-fabsf(v)));
}
// fp32 -> bf16 bits, round-to-nearest-even
__device__ __forceinline__ unsigned short f2bf(float f) {
    unsigned u = __builtin_bit_cast(unsigned, f);
    u += 0x7fffu + ((u >> 16) & 1u);
    return (unsigned short)(u >> 16);
}
__device__ __forceinline__ float bf2f(unsigned short u) {
    unsigned x = ((unsigned)u) << 16;
    return __builtin_bit_cast(float, x);
}

__device__ __forceinline__ void gld_lds16(const unsigned short* g, unsigned short* l) {
    __builtin_amdgcn_global_load_lds(
        (const __attribute__((address_space(1))) unsigned int*)g,
        (__attribute__((address_space(3))) unsigned int*)l, 16, 0, 0);
}

// ---- prep: fp32 -> bf16 (same layout), n4 = n/4 ----
__global__ __launch_bounds__(256) void f32_to_bf16_kernel(
    const float* __restrict__ in, unsigned short* __restrict__ out, int n4) {
    int i = blockIdx.x * 256 + threadIdx.x;
    if (i >= n4) return;
    float4 v = reinterpret_cast<const float4*>(in)[i];
    u16x4 o = {f2bf(v.x), f2bf(v.y), f2bf(v.z), f2bf(v.w)};
    reinterpret_cast<u16x4*>(out)[i] = o;
}

// ---- prep: transpose fp32 [R][Cc] -> bf16 [Cc][R] ----
__global__ __launch_bounds__(256) void transpose_bf16_kernel(
    const float* __restrict__ in, unsigned short* __restrict__ out, int R, int Cc) {
    __shared__ float t[32][33];
    const int tx = threadIdx.x & 31, ty = threadIdx.x >> 5; // 32 x 8
    const int c0 = blockIdx.x * 32, r0 = blockIdx.y * 32;
    for (int i = ty; i < 32; i += 8)
        t[i][tx] = in[(size_t)(r0 + i) * Cc + c0 + tx];
    __syncthreads();
    for (int i = ty; i < 32; i += 8)
        out[(size_t)(c0 + i) * R + r0 + tx] = f2bf(t[tx][i]);
}

// ---- bf16 MFMA GEMM: C[M,N] = A[M,K] @ Bt[N,K]^T ----
// 128x128 tile, 4 waves (2x2 of 64x64), BK=32, double-buffered LDS prefetch.
// LDS [row][32] row-major (64B rows) with chunk swizzle chunk' = chunk ^ ((row>>1)&3):
//   staging: lane-linear LDS dest, PRE-SWIZZLED global source (same row -> coalesced);
//   fragment read: kg ^ ((fr>>1)&3)  -> 2-way bank aliasing (free).
// EPI 0: plain store. EPI 1: n<DINNER -> C, else silu -> C2 (ldc=DINNER).
// EPI 2: softplus(v + bias[n]). CT = float | unsigned short (bf16).
template <int EPI, typename CT>
__global__ __launch_bounds__(256) void gemm_mfma(
    const unsigned short* __restrict__ A, const unsigned short* __restrict__ Bt,
    CT* __restrict__ C, CT* __restrict__ C2, const float* __restrict__ bias,
    int M, int N, int K) {
    __shared__ __align__(16) unsigned short As[2][4096];
    __shared__ __align__(16) unsigned short Bs[2][4096];
    const int tid = threadIdx.x;
    const int lane = tid & 63;
    const int wid = tid >> 6;
    const int wr = wid >> 1, wc = wid & 1;
    const int m0 = blockIdx.y * 128, n0 = blockIdx.x * 128;

    // staging geometry: round r covers LDS elems (tid + r*256)*8, i.e. rows r0/r1
    const int r0 = tid >> 2;              // 0..63
    const int r1 = r0 + 64;               // 64..127
    const int d0 = tid * 8;               // dest elem offset round 0
    const int d1 = d0 + 2048;             // dest elem offset round 1
    const int cs8 = (((tid & 3) ^ ((tid >> 3) & 3)) << 3); // swizzled src chunk (elems)

    f32x4 acc[4][4];
#pragma unroll
    for (int m = 0; m < 4; m++)
#pragma unroll
        for (int n = 0; n < 4; n++) acc[m][n] = (f32x4){0.f, 0.f, 0.f, 0.f};

    const int fr = lane & 15;
    const int kg = lane >> 4;
    const int kswz = ((kg ^ ((fr >> 1) & 3)) << 3); // swizzled read chunk (elems)
    const int nt = K / 32;

    // prologue: stage tile 0 into buffer 0
    gld_lds16(&A[(size_t)(m0 + r0) * K + cs8], &As[0][d0]);
    gld_lds16(&Bt[(size_t)(n0 + r0) * K + cs8], &Bs[0][d0]);
    gld_lds16(&A[(size_t)(m0 + r1) * K + cs8], &As[0][d1]);
    gld_lds16(&Bt[(size_t)(n0 + r1) * K + cs8], &Bs[0][d1]);
    __syncthreads();

    int cur = 0;
    for (int t = 0; t < nt; t++) {
        if (t + 1 < nt) { // issue next-tile prefetch BEFORE compute
            const int k0 = (t + 1) * 32;
            gld_lds16(&A[(size_t)(m0 + r0) * K + k0 + cs8], &As[cur ^ 1][d0]);
            gld_lds16(&Bt[(size_t)(n0 + r0) * K + k0 + cs8], &Bs[cur ^ 1][d0]);
            gld_lds16(&A[(size_t)(m0 + r1) * K + k0 + cs8], &As[cur ^ 1][d1]);
            gld_lds16(&Bt[(size_t)(n0 + r1) * K + k0 + cs8], &Bs[cur ^ 1][d1]);
        }
        short8 a[4], b[4];
#pragma unroll
        for (int m = 0; m < 4; m++)
            a[m] = *reinterpret_cast<const short8*>(
                &As[cur][(wr * 64 + m * 16 + fr) * 32 + kswz]);
#pragma unroll
        for (int n = 0; n < 4; n++)
            b[n] = *reinterpret_cast<const short8*>(
                &Bs[cur][(wc * 64 + n * 16 + fr) * 32 + kswz]);
#pragma unroll
        for (int m = 0; m < 4; m++)
#pragma unroll
            for (int n = 0; n < 4; n++)
                acc[m][n] = __builtin_amdgcn_mfma_f32_16x16x32_bf16(
                    a[m], b[n], acc[m][n], 0, 0, 0);
        __syncthreads(); // drains vmcnt (prefetch landed) + all reads of cur done
        cur ^= 1;
    }

    const int g4 = (lane >> 4) * 4;
#pragma unroll
    for (int m = 0; m < 4; m++)
#pragma unroll
        for (int n = 0; n < 4; n++)
#pragma unroll
            for (int j = 0; j < 4; j++) {
                int mm = m0 + wr * 64 + m * 16 + g4 + j;
                int nn = n0 + wc * 64 + n * 16 + fr;
                float v = acc[m][n][j];
                if (EPI == 2) v = softplus_f(v + bias[nn]);
                if (EPI == 1) {
                    if (nn < DINNER) {
                        if constexpr (sizeof(CT) == 2)
                            C[(size_t)mm * DINNER + nn] = f2bf(v);
                        else
                            C[(size_t)mm * DINNER + nn] = v;
                    } else {
                        float sv = silu_f(v);
                        if constexpr (sizeof(CT) == 2)
                            C2[(size_t)mm * DINNER + (nn - DINNER)] = f2bf(sv);
                        else
                            C2[(size_t)mm * DINNER + (nn - DINNER)] = sv;
                    }
                } else {
                    if constexpr (sizeof(CT) == 2)
                        C[(size_t)mm * N + nn] = f2bf(v);
                    else
                        C[(size_t)mm * N + nn] = v;
                }
            }
}

// ---- proj split-K MFMA: pp[kc][M][96] partial of xb_bf @ WxT^T ----
__global__ __launch_bounds__(256) void proj_splitk(
    const unsigned short* __restrict__ Abf,   // [M][DINNER] bf16
    const unsigned short* __restrict__ WxT,   // [NPROJ][DINNER] bf16
    float* __restrict__ pp) {
    const int lane = threadIdx.x & 63;
    const int wid = threadIdx.x >> 6;
    const int mt = wid >> 1;
    const int nh = wid & 1;
    const int m0 = blockIdx.x * 32;
    const int kc = blockIdx.y;
    const int fr = lane & 15;
    const int kg = lane >> 4;

    const size_t abase = (size_t)(m0 + mt * 16 + fr) * DINNER + kc * KCH + kg * 8;

    f32x4 acc[3];
#pragma unroll
    for (int i = 0; i < 3; i++) acc[i] = (f32x4){0.f, 0.f, 0.f, 0.f};

    for (int step = 0; step < KCH / 32; step++) {
        short8 a = *reinterpret_cast<const short8*>(&Abf[abase + step * 32]);
#pragma unroll
        for (int nt = 0; nt < 3; nt++) {
            int nrow = nh * 48 + nt * 16 + fr;
            short8 b = *reinterpret_cast<const short8*>(
                &WxT[(size_t)nrow * DINNER + kc * KCH + step * 32 + kg * 8]);
            acc[nt] = __builtin_amdgcn_mfma_f32_16x16x32_bf16(a, b, acc[nt], 0, 0, 0);
        }
    }
    const int g4 = (lane >> 4) * 4;
#pragma unroll
    for (int nt = 0; nt < 3; nt++)
#pragma unroll
        for (int j = 0; j < 4; j++) {
            int m = m0 + mt * 16 + g4 + j;
            int n = nh * 48 + nt * 16 + fr;
            pp[((size_t)kc * (BSZ * LSEQ) + m) * NPROJ + n] = acc[nt][j];
        }
}

// reduce split-K partials; emit fp32 proj + bf16 dt_in (cols < DTRANK)
__global__ __launch_bounds__(256) void proj_reduce(
    const float* __restrict__ pp, float* __restrict__ proj,
    unsigned short* __restrict__ dtin) {
    int i = blockIdx.x * 256 + threadIdx.x;
    if (i >= BSZ * LSEQ * NPROJ) return;
    float s = 0.f;
#pragma unroll
    for (int kc = 0; kc < KS; kc++)
        s += pp[(size_t)kc * BSZ * LSEQ * NPROJ + i];
    proj[i] = s;
    int m = i / NPROJ;
    int n = i - m * NPROJ;
    if (n < DTRANK) dtin[(size_t)m * DTRANK + n] = f2bf(s);
}

// causal depthwise conv (k=4) + bias + silu; bf16 in, bf16 out
__global__ __launch_bounds__(256) void conv_silu_kernel(
    const unsigned short* __restrict__ xin, const float* __restrict__ w,
    const float* __restrict__ bconv, unsigned short* __restrict__ xout) {
    int idx = blockIdx.x * 256 + threadIdx.x;
    if (idx >= BSZ * LSEQ * DINNER) return;
    int d = idx & (DINNER - 1);
    int bt = idx >> 11;
    int t = bt & (LSEQ - 1);
    float acc = bconv[d];
    const float* wr = &w[d * 4];
#pragma unroll
    for (int k = 0; k < 4; k++) {
        int tt = t + k - 3;
        if (tt >= 0) acc = fmaf(bf2f(xin[idx + (k - 3) * DINNER]), wr[k], acc);
    }
    xout[idx] = f2bf(silu_f(acc));
}

// ---- chunked selective scan (bf16 operands, fp32 state) ----
__global__ __launch_bounds__(256) void scan_pass1(
    const unsigned short* __restrict__ xb, const unsigned short* __restrict__ dt,
    const float* __restrict__ proj, const float* __restrict__ A_log,
    float* __restrict__ aprod, float* __restrict__ hend) {
    __shared__ float Bs[LC][DSTATE];
    const int tg = blockIdx.x * 256 + threadIdx.x;
    const int d = tg & (DINNER - 1);
    const int bc = tg >> 11;
    const int c = bc & (NC - 1);
    const int b = bc >> 5;

    for (int idx = threadIdx.x; idx < LC * DSTATE; idx += 256) {
        int ti = idx >> 4, j = idx & 15;
        Bs[ti][j] = proj[(size_t)(b * LSEQ + c * LC + ti) * NPROJ + DTRANK + j];
    }
    __syncthreads();

    float Av[DSTATE], h[DSTATE], ap[DSTATE];
#pragma unroll
    for (int s = 0; s < DSTATE; s++) {
        Av[s] = -expf(A_log[d * DSTATE + s]);
        h[s] = 0.f;
        ap[s] = 1.f;
    }

    for (int i = 0; i < LC; i++) {
        size_t base = (size_t)(b * LSEQ + c * LC + i) * DINNER + d;
        float dtv = bf2f(dt[base]);
        float xv = bf2f(xb[base]);
        float dx = dtv * xv;
#pragma unroll
        for (int s = 0; s < DSTATE; s++) {
            float dA = __expf(dtv * Av[s]);
            ap[s] *= dA;
            h[s] = fmaf(dA, h[s], dx * Bs[i][s]);
        }
    }

    size_t o = ((size_t)bc * DINNER + d) * DSTATE;
#pragma unroll
    for (int q = 0; q < 4; q++) {
        *reinterpret_cast<float4*>(&aprod[o + q * 4]) =
            make_float4(ap[4 * q], ap[4 * q + 1], ap[4 * q + 2], ap[4 * q + 3]);
        *reinterpret_cast<float4*>(&hend[o + q * 4]) =
            make_float4(h[4 * q], h[4 * q + 1], h[4 * q + 2], h[4 * q + 3]);
    }
}

__global__ __launch_bounds__(256) void scan_pass2(
    float* __restrict__ aprod, const float* __restrict__ hend) {
    const int tg = blockIdx.x * 256 + threadIdx.x;
    const int s = tg & (DSTATE - 1);
    const int d = (tg >> 4) & (DINNER - 1);
    const int b = tg >> 15;
    float h = 0.f;
    for (int c = 0; c < NC; c++) {
        size_t o = ((size_t)((b * NC + c) * DINNER) + d) * DSTATE + s;
        float a = aprod[o];
        float e = hend[o];
        aprod[o] = h;
        h = fmaf(a, h, e);
    }
}

__global__ __launch_bounds__(256) void scan_pass3(
    const unsigned short* __restrict__ xb, const unsigned short* __restrict__ dt,
    const float* __restrict__ proj, const float* __restrict__ hstart,
    const float* __restrict__ A_log, const float* __restrict__ Dp,
    const unsigned short* __restrict__ sz, unsigned short* __restrict__ ybf) {
    __shared__ float Bs[LC][DSTATE];
    __shared__ float Cs[LC][DSTATE];
    const int tg = blockIdx.x * 256 + threadIdx.x;
    const int d = tg & (DINNER - 1);
    const int bc = tg >> 11;
    const int c = bc & (NC - 1);
    const int b = bc >> 5;

    for (int idx = threadIdx.x; idx < LC * 2 * DSTATE; idx += 256) {
        int ti = idx >> 5, j = idx & 31;
        float v = proj[(size_t)(b * LSEQ + c * LC + ti) * NPROJ + DTRANK + j];
        if (j < DSTATE) Bs[ti][j] = v;
        else            Cs[ti][j - DSTATE] = v;
    }
    __syncthreads();

    float Av[DSTATE], h[DSTATE];
    size_t o = ((size_t)bc * DINNER + d) * DSTATE;
#pragma unroll
    for (int q = 0; q < 4; q++) {
        float4 hv = *reinterpret_cast<const float4*>(&hstart[o + q * 4]);
        h[4 * q] = hv.x; h[4 * q + 1] = hv.y; h[4 * q + 2] = hv.z; h[4 * q + 3] = hv.w;
    }
#pragma unroll
    for (int s = 0; s < DSTATE; s++)
        Av[s] = -expf(A_log[d * DSTATE + s]);
    const float Dd = Dp[d];

    for (int i = 0; i < LC; i++) {
        size_t base = (size_t)(b * LSEQ + c * LC + i) * DINNER + d;
        float dtv = bf2f(dt[base]);
        float xv = bf2f(xb[base]);
        float szv = bf2f(sz[base]);
        float dx = dtv * xv;
        float p = 0.f;
#pragma unroll
        for (int s = 0; s < DSTATE; s++) {
            float dA = __expf(dtv * Av[s]);
            h[s] = fmaf(dA, h[s], dx * Bs[i][s]);
            p = fmaf(h[s], Cs[i][s], p);
        }
        ybf[base] = f2bf((p + Dd * xv) * szv);
    }
}

extern "C" void kernel_launch(void* const* d_in, const int* in_sizes, int n_in,
                              void* d_out, int out_size, void* d_ws,
                              size_t ws_size, hipStream_t stream) {
    const float* x = (const float*)d_in[0];
    const float* W_in = (const float*)d_in[1];
    const float* conv_w = (const float*)d_in[2];
    const float* conv_b = (const float*)d_in[3];
    const float* W_xproj = (const float*)d_in[4];
    const float* W_dt = (const float*)d_in[5];
    const float* b_dt = (const float*)d_in[6];
    const float* A_log = (const float*)d_in[7];
    const float* Dp = (const float*)d_in[8];
    const float* W_out = (const float*)d_in[9];
    float* out = (float*)d_out;

    char* ws = (char*)d_ws;
    const size_t MB = 1u << 20;
    // [0,16M): pp (12.6M) -> later aprod(8M)+hend(8M)
    float* pp    = (float*)(ws);
    float* aprod = (float*)(ws);
    float* hend  = (float*)(ws + 8 * MB);
    unsigned short* xbpre_bf = (unsigned short*)(ws + 16 * MB);  // 16 MB
    unsigned short* sz_bf    = (unsigned short*)(ws + 32 * MB);  // 16 MB
    unsigned short* xb_bf    = (unsigned short*)(ws + 48 * MB);  // 16 MB
    unsigned short* dt_bf    = (unsigned short*)(ws + 64 * MB);  // 16 MB
    unsigned short* ybf      = (unsigned short*)(ws + 80 * MB);  // 8 MB
    float* projbuf           = (float*)(ws + 88 * MB);           // 1.5 MB
    unsigned short* dtin_bf  = (unsigned short*)(ws + 90 * MB);  // 0.5 MB
    unsigned short* xbf      = (unsigned short*)(ws + 91 * MB);  // 8 MB
    unsigned short* WinT     = (unsigned short*)(ws + 99 * MB);  // 8 MB
    unsigned short* WoutT    = (unsigned short*)(ws + 107 * MB); // 4 MB
    unsigned short* WxT      = (unsigned short*)(ws + 111 * MB); // 384 KB
    unsigned short* WdtT     = (unsigned short*)(ws + 112 * MB); // 256 KB

    const int M = BSZ * LSEQ; // 4096
    dim3 blk(256);

    // prep: bf16 conversions / weight transposes
    f32_to_bf16_kernel<<<dim3((M * DMODEL / 4 + 255) / 256), blk, 0, stream>>>(
        x, xbf, M * DMODEL / 4);
    transpose_bf16_kernel<<<dim3(2 * DINNER / 32, DMODEL / 32), blk, 0, stream>>>(
        W_in, WinT, DMODEL, 2 * DINNER);
    transpose_bf16_kernel<<<dim3(DMODEL / 32, DINNER / 32), blk, 0, stream>>>(
        W_out, WoutT, DINNER, DMODEL);
    transpose_bf16_kernel<<<dim3(NPROJ / 32, DINNER / 32), blk, 0, stream>>>(
        W_xproj, WxT, DINNER, NPROJ);
    transpose_bf16_kernel<<<dim3(DINNER / 32, DTRANK / 32), blk, 0, stream>>>(
        W_dt, WdtT, DTRANK, DINNER);

    // 1. xz = x @ W_in (bf16 MFMA, split: xbpre_bf | silu -> sz_bf)
    gemm_mfma<1, unsigned short><<<dim3((2 * DINNER) / 128, M / 128), blk, 0, stream>>>(
        xbf, WinT, xbpre_bf, sz_bf, nullptr, M, 2 * DINNER, DMODEL);

    // 2. conv + silu (bf16 -> bf16)
    conv_silu_kernel<<<dim3((M * DINNER) / 256), blk, 0, stream>>>(
        xbpre_bf, conv_w, conv_b, xb_bf);

    // 3. proj = xb @ W_xproj via split-K MFMA + reduce (emits fp32 proj + bf16 dt_in)
    proj_splitk<<<dim3(M / 32, KS), blk, 0, stream>>>(xb_bf, WxT, pp);
    proj_reduce<<<dim3((M * NPROJ) / 256), blk, 0, stream>>>(pp, projbuf, dtin_bf);

    // 4. dt = softplus(dt_in @ W_dt + b_dt) (bf16 MFMA, K=64)
    gemm_mfma<2, unsigned short><<<dim3(DINNER / 128, M / 128), blk, 0, stream>>>(
        dtin_bf, WdtT, dt_bf, nullptr, b_dt, M, DINNER, DTRANK);

    // 5. chunked selective scan
    const int nthreads1 = BSZ * NC * DINNER;
    scan_pass1<<<dim3(nthreads1 / 256), blk, 0, stream>>>(
        xb_bf, dt_bf, projbuf, A_log, aprod, hend);
    const int nthreads2 = BSZ * DINNER * DSTATE;
    scan_pass2<<<dim3(nthreads2 / 256), blk, 0, stream>>>(aprod, hend);
    scan_pass3<<<dim3(nthreads1 / 256), blk, 0, stream>>>(
        xb_bf, dt_bf, projbuf, aprod, A_log, Dp, sz_bf, ybf);

    // 6. out = y @ W_out (bf16 MFMA, fp32 store)
    gemm_mfma<0, float><<<dim3(DMODEL / 128, M / 128), blk, 0, stream>>>(
        ybf, WoutT, out, nullptr, nullptr, M, DMODEL, DINNER);
}